// Round 2
// baseline (2803.284 us; speedup 1.0000x reference)
//
#include <hip/hip_runtime.h>
#include <math.h>
#include <cstddef>

// Problem constants (match reference)
#define SEQL   2048
#define DMODEL 128
#define NHEADS 4
#define DINNER 256
#define DSTATE 128
#define DTRANK 8
#define KWIDTH 128   // big conv kernel size
#define HT     (NHEADS*SEQL)   // 8192 rows for mamba GEMMs

// ---------------------------------------------------------------------------
// Big conv as K-split tiled GEMM.
// X: [I_TOTAL][SEQL] (flat reinterpretation of the reference's reshape)
// W: [O_TOTAL][I_TOTAL][KWIDTH]
// Yp: [KSPLIT][O_TOTAL*SEQL] partial sums (no bias, no activation)
// y[o,t] = sum_{i,k} W[o][i][k] * X[i][t+k-63]   (SAME padding: pad_low=63)
// Block: 64 o x 256 t, 512 threads, per-thread 4o x 8t register tile.
// ---------------------------------------------------------------------------
template<int O_TOTAL, int I_TOTAL, int KSPLIT>
__global__ __launch_bounds__(512)
void conv_partial(const float* __restrict__ X, const float* __restrict__ W,
                  float* __restrict__ Yp)
{
    constexpr int BO = 64, BT = 256;
    constexpr int IPS = I_TOTAL / KSPLIT;
    __shared__ __align__(16) float Als[KWIDTH][BO + 4];  // [k][o], stride 68 (272B, 16B aligned)
    __shared__ __align__(16) float Xls[BT + KWIDTH];     // 384-entry window

    const int o0 = blockIdx.x * BO;
    const int t0 = blockIdx.y * BT;
    const int i0 = blockIdx.z * IPS;
    const int tid = threadIdx.x;
    const int ty = tid >> 5;          // 0..15 -> o
    const int tx = tid & 31;          // 0..31 -> t
    const int oL = ty * 4;
    const int tL = tx * 8;

    float acc[4][8];
    #pragma unroll
    for (int a = 0; a < 4; ++a)
        #pragma unroll
        for (int b = 0; b < 8; ++b) acc[a][b] = 0.f;

    for (int i = i0; i < i0 + IPS; ++i) {
        __syncthreads();
        // stage weights: W[o0+o][i][k] -> Als[k][o]  (64*128 elems, 16/thread)
        {
            const int o  = tid >> 3;          // 0..63
            const int kb = (tid & 7) * 16;    // 0,16,...,112
            const float* wrow = W + ((size_t)(o0 + o) * I_TOTAL + i) * KWIDTH + kb;
            #pragma unroll
            for (int j4 = 0; j4 < 4; ++j4) {
                float4 v = *reinterpret_cast<const float4*>(wrow + j4 * 4);
                Als[kb + j4*4 + 0][o] = v.x;
                Als[kb + j4*4 + 1][o] = v.y;
                Als[kb + j4*4 + 2][o] = v.z;
                Als[kb + j4*4 + 3][o] = v.w;
            }
        }
        // stage x window: positions t0-63 .. t0+320 (383 used + 1 pad slot)
        if (tid < BT + KWIDTH) {
            int p = t0 - 63 + tid;
            Xls[tid] = (p >= 0 && p < SEQL) ? X[(size_t)i * SEQL + p] : 0.f;
        }
        __syncthreads();

        #pragma unroll 1
        for (int k4 = 0; k4 < KWIDTH / 4; ++k4) {
            float bw[12];
            const float* bp = &Xls[k4 * 4 + tL];
            *reinterpret_cast<float4*>(bw + 0) = *reinterpret_cast<const float4*>(bp + 0);
            *reinterpret_cast<float4*>(bw + 4) = *reinterpret_cast<const float4*>(bp + 4);
            *reinterpret_cast<float4*>(bw + 8) = *reinterpret_cast<const float4*>(bp + 8);
            #pragma unroll
            for (int kk = 0; kk < 4; ++kk) {
                float4 a4 = *reinterpret_cast<const float4*>(&Als[k4 * 4 + kk][oL]);
                float av[4] = {a4.x, a4.y, a4.z, a4.w};
                #pragma unroll
                for (int m = 0; m < 4; ++m)
                    #pragma unroll
                    for (int j = 0; j < 8; ++j)
                        acc[m][j] += av[m] * bw[kk + j];
            }
        }
    }

    float* outp = Yp + (size_t)blockIdx.z * (O_TOTAL * SEQL);
    #pragma unroll
    for (int m = 0; m < 4; ++m) {
        #pragma unroll
        for (int j = 0; j < 8; j += 4) {
            float4 v = {acc[m][j], acc[m][j+1], acc[m][j+2], acc[m][j+3]};
            *reinterpret_cast<float4*>(outp + (size_t)(o0 + oL + m) * SEQL + t0 + tL + j) = v;
        }
    }
}

// combine K-split partials + bias + silu
template<int KSPLIT>
__global__ void conv_combine_silu(const float* __restrict__ Yp, const float* __restrict__ bias,
                                  float* __restrict__ out, int total)
{
    int f = blockIdx.x * 256 + threadIdx.x;
    if (f >= total) return;
    float s = bias[f >> 11];              // o = f / 2048
    #pragma unroll
    for (int z = 0; z < KSPLIT; ++z) s += Yp[(size_t)z * total + f];
    out[f] = s / (1.f + __expf(-s));      // silu
}

// ---------------------------------------------------------------------------
// Generic fp32 GEMM, C[M][N] = A[M][K] * B[N][K]^T (both row-major).
// 64x64 tile, 256 threads, 4x4 per thread, BK=16.
// ---------------------------------------------------------------------------
__global__ __launch_bounds__(256)
void gemm_nt(const float* __restrict__ A, const float* __restrict__ B,
             float* __restrict__ C, int M, int N, int K)
{
    constexpr int BM = 64, BN = 64, BK = 16;
    __shared__ __align__(16) float As[BK][BM + 4];
    __shared__ __align__(16) float Bs[BK][BN + 4];
    const int m0 = blockIdx.x * BM, n0 = blockIdx.y * BN;
    const int tid = threadIdx.x;
    const int ty = tid >> 4, tx = tid & 15;
    float acc[4][4] = {};

    for (int k0 = 0; k0 < K; k0 += BK) {
        __syncthreads();
        {
            int r  = tid >> 2;              // 0..63
            int kb = (tid & 3) * 4;         // 0,4,8,12
            float4 va = *reinterpret_cast<const float4*>(A + (size_t)(m0 + r) * K + k0 + kb);
            As[kb+0][r] = va.x; As[kb+1][r] = va.y; As[kb+2][r] = va.z; As[kb+3][r] = va.w;
            float4 vb = make_float4(0.f, 0.f, 0.f, 0.f);
            if (n0 + r < N)
                vb = *reinterpret_cast<const float4*>(B + (size_t)(n0 + r) * K + k0 + kb);
            Bs[kb+0][r] = vb.x; Bs[kb+1][r] = vb.y; Bs[kb+2][r] = vb.z; Bs[kb+3][r] = vb.w;
        }
        __syncthreads();
        #pragma unroll
        for (int k = 0; k < BK; ++k) {
            float4 a4 = *reinterpret_cast<const float4*>(&As[k][ty * 4]);
            float4 b4 = *reinterpret_cast<const float4*>(&Bs[k][tx * 4]);
            float av[4] = {a4.x, a4.y, a4.z, a4.w};
            float bv[4] = {b4.x, b4.y, b4.z, b4.w};
            #pragma unroll
            for (int i = 0; i < 4; ++i)
                #pragma unroll
                for (int j = 0; j < 4; ++j) acc[i][j] += av[i] * bv[j];
        }
    }
    #pragma unroll
    for (int i = 0; i < 4; ++i) {
        int m = m0 + ty * 4 + i;
        #pragma unroll
        for (int j = 0; j < 4; ++j) {
            int n = n0 + tx * 4 + j;
            if (n < N) C[(size_t)m * N + n] = acc[i][j];
        }
    }
}

// ---------------------------------------------------------------------------
// depthwise conv (7 taps) + silu. dir=0: causal x[t-6+k]; dir=1: anticausal x[t+6-k]
// xz: [HT][512] (xs = cols 0..255, z = cols 256..511); xc: [HT][256]
// ---------------------------------------------------------------------------
__global__ void dwconv_silu(const float* __restrict__ xz, const float* __restrict__ w7,
                            const float* __restrict__ cb, float* __restrict__ xc, int dir)
{
    int idx = blockIdx.x * 256 + threadIdx.x;
    if (idx >= HT * 256) return;
    int c = idx & 255;
    int ht = idx >> 8;
    int h = ht >> 11, t = ht & 2047;
    float s = cb[c];
    #pragma unroll
    for (int k = 0; k < 7; ++k) {
        int tt = dir ? (t + 6 - k) : (t - 6 + k);
        if (tt >= 0 && tt < SEQL)
            s += w7[c * 7 + k] * xz[((size_t)(h << 11) + tt) * 512 + c];
    }
    xc[idx] = s / (1.f + __expf(-s));
}

// delta = softplus(dt @ dt_w^T + dt_b);  dbc: [HT][264], dt = cols 0..7
__global__ void delta_softplus(const float* __restrict__ dbc, const float* __restrict__ dtw,
                               const float* __restrict__ dtb, float* __restrict__ delta)
{
    int idx = blockIdx.x * 256 + threadIdx.x;
    if (idx >= HT * 256) return;
    int c = idx & 255;
    int ht = idx >> 8;
    const float* dr = dbc + (size_t)ht * 264;
    float s = dtb[c];
    #pragma unroll
    for (int r = 0; r < 8; ++r) s += dr[r] * dtw[c * 8 + r];
    // stable softplus
    delta[idx] = (s > 20.f) ? s : log1pf(__expf(s));
}

// ---------------------------------------------------------------------------
// selective scan, one wave per (d, h, dir); lane owns states n=lane and n=lane+64.
// ---------------------------------------------------------------------------
__global__ __launch_bounds__(64)
void scan_kernel(const float* __restrict__ del_f, const float* __restrict__ dbc_f,
                 const float* __restrict__ xc_f, float* __restrict__ ys_f,
                 const float* __restrict__ del_b, const float* __restrict__ dbc_b,
                 const float* __restrict__ xc_b, float* __restrict__ ys_b,
                 const float* __restrict__ A_log)
{
    const int d   = blockIdx.x;   // 0..255
    const int h   = blockIdx.y;   // 0..3
    const int dir = blockIdx.z;   // 0 fwd, 1 bwd
    const float* del = dir ? del_b : del_f;
    const float* dbc = dir ? dbc_b : dbc_f;
    const float* xc  = dir ? xc_b  : xc_f;
    float* ys        = dir ? ys_b  : ys_f;
    const int lane = threadIdx.x;

    const float A0 = -__expf(A_log[d * 128 + lane]);
    const float A1 = -__expf(A_log[d * 128 + 64 + lane]);
    float h0 = 0.f, h1 = 0.f;

    int t = dir ? 2047 : 0;
    size_t ht = (size_t)h * 2048 + t;
    float rd = del[ht * 256 + d];
    float ru = xc[ht * 256 + d];
    const float* p0 = dbc + ht * 264;
    float rB0 = p0[8 + lane],   rB1 = p0[72 + lane];
    float rC0 = p0[136 + lane], rC1 = p0[200 + lane];

    for (int s = 0; s < 2048; ++s) {
        float dlt = rd, u = ru, B0 = rB0, B1 = rB1, C0 = rC0, C1 = rC1;
        size_t ht_cur = ht;
        if (s + 1 < 2048) {   // prefetch next step while computing this one
            t = dir ? (2047 - (s + 1)) : (s + 1);
            ht = (size_t)h * 2048 + t;
            rd = del[ht * 256 + d];
            ru = xc[ht * 256 + d];
            const float* p = dbc + ht * 264;
            rB0 = p[8 + lane];   rB1 = p[72 + lane];
            rC0 = p[136 + lane]; rC1 = p[200 + lane];
        }
        float du = dlt * u;
        h0 = __expf(dlt * A0) * h0 + du * B0;
        h1 = __expf(dlt * A1) * h1 + du * B1;
        float v = h0 * C0 + h1 * C1;
        #pragma unroll
        for (int off = 32; off; off >>= 1) v += __shfl_down(v, off);
        if (lane == 0) ys[ht_cur * 256 + d] = v;
    }
}

// y = (ys + xc*D) * silu(z)   (written in place over ys)
__global__ void ycombine(const float* ysin, const float* __restrict__ xc,
                         const float* __restrict__ xz, const float* __restrict__ Dp,
                         float* yout)
{
    int idx = blockIdx.x * 256 + threadIdx.x;
    if (idx >= HT * 256) return;
    int c = idx & 255;
    size_t ht = idx >> 8;
    float z = xz[ht * 512 + 256 + c];
    float y = (ysin[idx] + xc[idx] * Dp[c]) * (z / (1.f + __expf(-z)));
    yout[idx] = y;
}

// xn = rmsnorm(xf + xb) * w ; one 64-lane wave per 128-elem row
__global__ __launch_bounds__(256)
void rmsnorm_add(const float* __restrict__ xf, const float* __restrict__ xb,
                 const float* __restrict__ w, float* __restrict__ xn)
{
    int row  = blockIdx.x * 4 + (threadIdx.x >> 6);
    int lane = threadIdx.x & 63;
    size_t base = (size_t)row * 128;
    float a0 = xf[base + lane]      + xb[base + lane];
    float a1 = xf[base + 64 + lane] + xb[base + 64 + lane];
    float ss = a0 * a0 + a1 * a1;
    #pragma unroll
    for (int off = 32; off; off >>= 1) ss += __shfl_xor(ss, off);
    float r = rsqrtf(ss / 128.f + 1e-8f);
    xn[base + lane]      = a0 * r * w[lane];
    xn[base + 64 + lane] = a1 * r * w[64 + lane];
}

// ---------------------------------------------------------------------------
extern "C" void kernel_launch(void* const* d_in, const int* in_sizes, int n_in,
                              void* d_out, int out_size, void* d_ws, size_t ws_size,
                              hipStream_t stream)
{
    const float* x        = (const float*)d_in[0];
    const float* icw      = (const float*)d_in[1];
    const float* icb      = (const float*)d_in[2];
    const float* ocw      = (const float*)d_in[3];
    const float* ocb      = (const float*)d_in[4];
    const float* in_proj  = (const float*)d_in[5];
    const float* mconv_w  = (const float*)d_in[6];
    const float* mconv_b  = (const float*)d_in[7];
    const float* x_proj   = (const float*)d_in[8];
    const float* dt_w     = (const float*)d_in[9];
    const float* dt_b     = (const float*)d_in[10];
    const float* A_log    = (const float*)d_in[11];
    const float* Dp       = (const float*)d_in[12];
    const float* out_proj = (const float*)d_in[13];
    const float* norm_w   = (const float*)d_in[14];
    float* out = (float*)d_out;
    (void)in_sizes; (void)n_in; (void)out_size; (void)ws_size;

    float* w = (float*)d_ws;
    size_t off = 0;
    auto alloc = [&](size_t n) { float* p = w + off; off += n; return p; };
    float* p12   = alloc((size_t)4 * 1048576);  // conv1 partials (4x1M) reused as conv2 partials (16x256K)
    float* xp    = alloc(1048576);              // conv1 out (=mamba input, flat [h][t][d])
    float* xz    = alloc((size_t)HT * 512);
    float* xc_f  = alloc((size_t)HT * 256);
    float* xc_b  = alloc((size_t)HT * 256);
    float* dbc_f = alloc((size_t)HT * 264);
    float* dbc_b = alloc((size_t)HT * 264);
    float* del_f = alloc((size_t)HT * 256);
    float* del_b = alloc((size_t)HT * 256);
    float* ys_f  = alloc((size_t)HT * 256);
    float* ys_b  = alloc((size_t)HT * 256);
    float* xfo   = alloc((size_t)HT * 128);
    float* xbo   = alloc((size_t)HT * 128);
    float* xn    = alloc((size_t)HT * 128);

    // 1) input conv (512x2048 out, K=128x128) + bias + silu
    conv_partial<512, 128, 4><<<dim3(8, 8, 4), 512, 0, stream>>>(x, icw, p12);
    conv_combine_silu<4><<<4096, 256, 0, stream>>>(p12, icb, xp, 512 * 2048);

    // 2) shared in_proj GEMM: xz = xp @ in_proj^T   (8192x512, K=128)
    gemm_nt<<<dim3(128, 8), 256, 0, stream>>>(xp, in_proj, xz, HT, 512, 128);

    // 3) depthwise conv + silu, both directions
    dwconv_silu<<<8192, 256, 0, stream>>>(xz, mconv_w, mconv_b, xc_f, 0);
    dwconv_silu<<<8192, 256, 0, stream>>>(xz, mconv_w, mconv_b, xc_b, 1);

    // 4) x_proj GEMMs: dbc = xc @ x_proj^T  (8192x264, K=256)
    gemm_nt<<<dim3(128, 5), 256, 0, stream>>>(xc_f, x_proj, dbc_f, HT, 264, 256);
    gemm_nt<<<dim3(128, 5), 256, 0, stream>>>(xc_b, x_proj, dbc_b, HT, 264, 256);

    // 5) delta = softplus(dt @ dt_w^T + dt_b)
    delta_softplus<<<8192, 256, 0, stream>>>(dbc_f, dt_w, dt_b, del_f);
    delta_softplus<<<8192, 256, 0, stream>>>(dbc_b, dt_w, dt_b, del_b);

    // 6) selective scan, fwd+bwd concurrently
    scan_kernel<<<dim3(256, 4, 2), 64, 0, stream>>>(del_f, dbc_f, xc_f, ys_f,
                                                    del_b, dbc_b, xc_b, ys_b, A_log);

    // 7) y = (ys + xc*D) * silu(z)  (in place)
    ycombine<<<8192, 256, 0, stream>>>(ys_f, xc_f, xz, Dp, ys_f);
    ycombine<<<8192, 256, 0, stream>>>(ys_b, xc_b, xz, Dp, ys_b);

    // 8) out_proj GEMMs (8192x128, K=256)
    gemm_nt<<<dim3(128, 2), 256, 0, stream>>>(ys_f, out_proj, xfo, HT, 128, 256);
    gemm_nt<<<dim3(128, 2), 256, 0, stream>>>(ys_b, out_proj, xbo, HT, 128, 256);

    // 9) rmsnorm(xf + xb)
    rmsnorm_add<<<2048, 256, 0, stream>>>(xfo, xbo, norm_w, xn);

    // 10) output conv (128x2048 out, K=512x128) + bias + silu -> d_out
    conv_partial<128, 512, 16><<<dim3(2, 8, 16), 512, 0, stream>>>(xn, ocw, p12);
    conv_combine_silu<16><<<1024, 256, 0, stream>>>(p12, ocb, out, 128 * 2048);
}

// Round 3
// 2199.540 us; speedup vs baseline: 1.2745x; 1.2745x over previous
//
#include <hip/hip_runtime.h>
#include <math.h>
#include <cstddef>

// Problem constants (match reference)
#define SEQL   2048
#define DMODEL 128
#define NHEADS 4
#define DINNER 256
#define DSTATE 128
#define DTRANK 8
#define KWIDTH 128   // big conv kernel size
#define HT     (NHEADS*SEQL)   // 8192 rows for mamba GEMMs
#define NCHUNK 16
#define CHUNK  128   // SEQL / NCHUNK

// ---------------------------------------------------------------------------
// Big conv as K-split tiled GEMM.
// X: [I_TOTAL][SEQL], W: [O_TOTAL][I_TOTAL][KWIDTH]
// Yp: [KSPLIT][O_TOTAL*SEQL] partial sums
// y[o,t] = sum_{i,k} W[o][i][k] * X[i][t+k-63]   (SAME padding: pad_low=63)
// ---------------------------------------------------------------------------
template<int O_TOTAL, int I_TOTAL, int KSPLIT>
__global__ __launch_bounds__(512)
void conv_partial(const float* __restrict__ X, const float* __restrict__ W,
                  float* __restrict__ Yp)
{
    constexpr int BO = 64, BT = 256;
    constexpr int IPS = I_TOTAL / KSPLIT;
    __shared__ __align__(16) float Als[KWIDTH][BO + 4];
    __shared__ __align__(16) float Xls[BT + KWIDTH];

    const int o0 = blockIdx.x * BO;
    const int t0 = blockIdx.y * BT;
    const int i0 = blockIdx.z * IPS;
    const int tid = threadIdx.x;
    const int ty = tid >> 5;
    const int tx = tid & 31;
    const int oL = ty * 4;
    const int tL = tx * 8;

    float acc[4][8];
    #pragma unroll
    for (int a = 0; a < 4; ++a)
        #pragma unroll
        for (int b = 0; b < 8; ++b) acc[a][b] = 0.f;

    for (int i = i0; i < i0 + IPS; ++i) {
        __syncthreads();
        {
            const int o  = tid >> 3;
            const int kb = (tid & 7) * 16;
            const float* wrow = W + ((size_t)(o0 + o) * I_TOTAL + i) * KWIDTH + kb;
            #pragma unroll
            for (int j4 = 0; j4 < 4; ++j4) {
                float4 v = *reinterpret_cast<const float4*>(wrow + j4 * 4);
                Als[kb + j4*4 + 0][o] = v.x;
                Als[kb + j4*4 + 1][o] = v.y;
                Als[kb + j4*4 + 2][o] = v.z;
                Als[kb + j4*4 + 3][o] = v.w;
            }
        }
        if (tid < BT + KWIDTH) {
            int p = t0 - 63 + tid;
            Xls[tid] = (p >= 0 && p < SEQL) ? X[(size_t)i * SEQL + p] : 0.f;
        }
        __syncthreads();

        #pragma unroll 1
        for (int k4 = 0; k4 < KWIDTH / 4; ++k4) {
            float bw[12];
            const float* bp = &Xls[k4 * 4 + tL];
            *reinterpret_cast<float4*>(bw + 0) = *reinterpret_cast<const float4*>(bp + 0);
            *reinterpret_cast<float4*>(bw + 4) = *reinterpret_cast<const float4*>(bp + 4);
            *reinterpret_cast<float4*>(bw + 8) = *reinterpret_cast<const float4*>(bp + 8);
            #pragma unroll
            for (int kk = 0; kk < 4; ++kk) {
                float4 a4 = *reinterpret_cast<const float4*>(&Als[k4 * 4 + kk][oL]);
                float av[4] = {a4.x, a4.y, a4.z, a4.w};
                #pragma unroll
                for (int m = 0; m < 4; ++m)
                    #pragma unroll
                    for (int j = 0; j < 8; ++j)
                        acc[m][j] += av[m] * bw[kk + j];
            }
        }
    }

    float* outp = Yp + (size_t)blockIdx.z * (O_TOTAL * SEQL);
    #pragma unroll
    for (int m = 0; m < 4; ++m) {
        #pragma unroll
        for (int j = 0; j < 8; j += 4) {
            float4 v = {acc[m][j], acc[m][j+1], acc[m][j+2], acc[m][j+3]};
            *reinterpret_cast<float4*>(outp + (size_t)(o0 + oL + m) * SEQL + t0 + tL + j) = v;
        }
    }
}

template<int KSPLIT>
__global__ void conv_combine_silu(const float* __restrict__ Yp, const float* __restrict__ bias,
                                  float* __restrict__ out, int total)
{
    int f = blockIdx.x * 256 + threadIdx.x;
    if (f >= total) return;
    float s = bias[f >> 11];
    #pragma unroll
    for (int z = 0; z < KSPLIT; ++z) s += Yp[(size_t)z * total + f];
    out[f] = s / (1.f + __expf(-s));
}

// ---------------------------------------------------------------------------
// Generic fp32 GEMM, C[M][N] = A[M][K] * B[N][K]^T
// ---------------------------------------------------------------------------
__global__ __launch_bounds__(256)
void gemm_nt(const float* __restrict__ A, const float* __restrict__ B,
             float* __restrict__ C, int M, int N, int K)
{
    constexpr int BM = 64, BN = 64, BK = 16;
    __shared__ __align__(16) float As[BK][BM + 4];
    __shared__ __align__(16) float Bs[BK][BN + 4];
    const int m0 = blockIdx.x * BM, n0 = blockIdx.y * BN;
    const int tid = threadIdx.x;
    const int ty = tid >> 4, tx = tid & 15;
    float acc[4][4] = {};

    for (int k0 = 0; k0 < K; k0 += BK) {
        __syncthreads();
        {
            int r  = tid >> 2;
            int kb = (tid & 3) * 4;
            float4 va = *reinterpret_cast<const float4*>(A + (size_t)(m0 + r) * K + k0 + kb);
            As[kb+0][r] = va.x; As[kb+1][r] = va.y; As[kb+2][r] = va.z; As[kb+3][r] = va.w;
            float4 vb = make_float4(0.f, 0.f, 0.f, 0.f);
            if (n0 + r < N)
                vb = *reinterpret_cast<const float4*>(B + (size_t)(n0 + r) * K + k0 + kb);
            Bs[kb+0][r] = vb.x; Bs[kb+1][r] = vb.y; Bs[kb+2][r] = vb.z; Bs[kb+3][r] = vb.w;
        }
        __syncthreads();
        #pragma unroll
        for (int k = 0; k < BK; ++k) {
            float4 a4 = *reinterpret_cast<const float4*>(&As[k][ty * 4]);
            float4 b4 = *reinterpret_cast<const float4*>(&Bs[k][tx * 4]);
            float av[4] = {a4.x, a4.y, a4.z, a4.w};
            float bv[4] = {b4.x, b4.y, b4.z, b4.w};
            #pragma unroll
            for (int i = 0; i < 4; ++i)
                #pragma unroll
                for (int j = 0; j < 4; ++j) acc[i][j] += av[i] * bv[j];
        }
    }
    #pragma unroll
    for (int i = 0; i < 4; ++i) {
        int m = m0 + ty * 4 + i;
        #pragma unroll
        for (int j = 0; j < 4; ++j) {
            int n = n0 + tx * 4 + j;
            if (n < N) C[(size_t)m * N + n] = acc[i][j];
        }
    }
}

// ---------------------------------------------------------------------------
// depthwise conv (7 taps) + silu
// ---------------------------------------------------------------------------
__global__ void dwconv_silu(const float* __restrict__ xz, const float* __restrict__ w7,
                            const float* __restrict__ cb, float* __restrict__ xc, int dir)
{
    int idx = blockIdx.x * 256 + threadIdx.x;
    if (idx >= HT * 256) return;
    int c = idx & 255;
    int ht = idx >> 8;
    int h = ht >> 11, t = ht & 2047;
    float s = cb[c];
    #pragma unroll
    for (int k = 0; k < 7; ++k) {
        int tt = dir ? (t + 6 - k) : (t - 6 + k);
        if (tt >= 0 && tt < SEQL)
            s += w7[c * 7 + k] * xz[((size_t)(h << 11) + tt) * 512 + c];
    }
    xc[idx] = s / (1.f + __expf(-s));
}

__global__ void delta_softplus(const float* __restrict__ dbc, const float* __restrict__ dtw,
                               const float* __restrict__ dtb, float* __restrict__ delta)
{
    int idx = blockIdx.x * 256 + threadIdx.x;
    if (idx >= HT * 256) return;
    int c = idx & 255;
    int ht = idx >> 8;
    const float* dr = dbc + (size_t)ht * 264;
    float s = dtb[c];
    #pragma unroll
    for (int r = 0; r < 8; ++r) s += dr[r] * dtw[c * 8 + r];
    delta[idx] = (s > 20.f) ? s : log1pf(__expf(s));
}

// ---------------------------------------------------------------------------
// Chunked selective scan (3 passes).
// Recurrence per (dir,h,d,n): h_t = exp(delta_t,d * A_d,n) * h_{t-1} + delta_t,d*u_t,d*B_t,n
// y_t,d = sum_n h_t,d,n * C_t,n.  "scan order" index g: fwd t=g, bwd t=2047-g.
// Pass1: per (dir,h,chunk,d): local scan from 0 -> Q, product of a -> P.
// Pass2: per (dir,h,d,n): combine over chunks; chunk-start state written over Q.
// Pass3: per (dir,h,chunk,d): recurrence from true start state, emit y.
// P/Q layout: [dirh(8)][chunk(16)][d(256)][n(128)]
// ---------------------------------------------------------------------------
__global__ __launch_bounds__(256)
void scan_pass1(const float* __restrict__ del_f, const float* __restrict__ dbc_f,
                const float* __restrict__ xc_f,
                const float* __restrict__ del_b, const float* __restrict__ dbc_b,
                const float* __restrict__ xc_b,
                const float* __restrict__ A_log, float* __restrict__ P, float* __restrict__ Q)
{
    const int wid = threadIdx.x >> 6, lane = threadIdx.x & 63;
    const int d  = blockIdx.x * 4 + wid;
    const int c  = blockIdx.y;
    const int hd = blockIdx.z;                 // dir = hd>>2, h = hd&3
    const int dir = hd >> 2, h = hd & 3;
    const float* del = dir ? del_b : del_f;
    const float* dbc = dir ? dbc_b : dbc_f;
    const float* xc  = dir ? xc_b  : xc_f;

    const float A0 = -__expf(A_log[d * 128 + lane]);
    const float A1 = -__expf(A_log[d * 128 + 64 + lane]);
    float h0 = 0.f, h1 = 0.f, p0 = 1.f, p1 = 1.f;

    for (int s = 0; s < CHUNK; ++s) {
        int g = c * CHUNK + s;
        int t = dir ? (2047 - g) : g;
        size_t ht = (size_t)h * 2048 + t;
        float dlt = del[ht * 256 + d];
        float u   = xc[ht * 256 + d];
        const float* pp = dbc + ht * 264;
        float B0 = pp[8 + lane], B1 = pp[72 + lane];
        float du = dlt * u;
        float a0 = __expf(dlt * A0), a1 = __expf(dlt * A1);
        h0 = a0 * h0 + du * B0;
        h1 = a1 * h1 + du * B1;
        p0 *= a0; p1 *= a1;
    }
    size_t base = (((size_t)hd * NCHUNK + c) * 256 + d) * 128;
    P[base + lane] = p0;  P[base + 64 + lane] = p1;
    Q[base + lane] = h0;  Q[base + 64 + lane] = h1;
}

// thread per (dirh,d,n) element; sequential over the 16 chunks.
// Writes chunk-START state in place over Q.
__global__ void scan_pass2(const float* __restrict__ P, float* __restrict__ Q)
{
    int idx = blockIdx.x * 256 + threadIdx.x;   // 8*256*128 = 262144
    int hd = idx >> 15;
    int dn = idx & 32767;
    size_t b0 = (size_t)hd * NCHUNK * 32768 + dn;
    float hcur = 0.f;
    for (int c = 0; c < NCHUNK; ++c) {
        size_t o = b0 + (size_t)c * 32768;
        float q = Q[o];
        Q[o] = hcur;                     // chunk-start state
        hcur = P[o] * hcur + q;          // state after chunk c
    }
}

__global__ __launch_bounds__(256)
void scan_pass3(const float* __restrict__ del_f, const float* __restrict__ dbc_f,
                const float* __restrict__ xc_f, float* __restrict__ ys_f,
                const float* __restrict__ del_b, const float* __restrict__ dbc_b,
                const float* __restrict__ xc_b, float* __restrict__ ys_b,
                const float* __restrict__ A_log, const float* __restrict__ H)
{
    const int wid = threadIdx.x >> 6, lane = threadIdx.x & 63;
    const int d  = blockIdx.x * 4 + wid;
    const int c  = blockIdx.y;
    const int hd = blockIdx.z;
    const int dir = hd >> 2, h = hd & 3;
    const float* del = dir ? del_b : del_f;
    const float* dbc = dir ? dbc_b : dbc_f;
    const float* xc  = dir ? xc_b  : xc_f;
    float* ys        = dir ? ys_b  : ys_f;

    const float A0 = -__expf(A_log[d * 128 + lane]);
    const float A1 = -__expf(A_log[d * 128 + 64 + lane]);
    size_t base = (((size_t)hd * NCHUNK + c) * 256 + d) * 128;
    float h0 = H[base + lane], h1 = H[base + 64 + lane];

    for (int s = 0; s < CHUNK; ++s) {
        int g = c * CHUNK + s;
        int t = dir ? (2047 - g) : g;
        size_t ht = (size_t)h * 2048 + t;
        float dlt = del[ht * 256 + d];
        float u   = xc[ht * 256 + d];
        const float* pp = dbc + ht * 264;
        float B0 = pp[8 + lane],   B1 = pp[72 + lane];
        float C0 = pp[136 + lane], C1 = pp[200 + lane];
        float du = dlt * u;
        h0 = __expf(dlt * A0) * h0 + du * B0;
        h1 = __expf(dlt * A1) * h1 + du * B1;
        float v = h0 * C0 + h1 * C1;
        #pragma unroll
        for (int off = 32; off; off >>= 1) v += __shfl_down(v, off);
        if (lane == 0) ys[ht * 256 + d] = v;
    }
}

__global__ void ycombine(const float* ysin, const float* __restrict__ xc,
                         const float* __restrict__ xz, const float* __restrict__ Dp,
                         float* yout)
{
    int idx = blockIdx.x * 256 + threadIdx.x;
    if (idx >= HT * 256) return;
    int c = idx & 255;
    size_t ht = idx >> 8;
    float z = xz[ht * 512 + 256 + c];
    float y = (ysin[idx] + xc[idx] * Dp[c]) * (z / (1.f + __expf(-z)));
    yout[idx] = y;
}

__global__ __launch_bounds__(256)
void rmsnorm_add(const float* __restrict__ xf, const float* __restrict__ xb,
                 const float* __restrict__ w, float* __restrict__ xn)
{
    int row  = blockIdx.x * 4 + (threadIdx.x >> 6);
    int lane = threadIdx.x & 63;
    size_t base = (size_t)row * 128;
    float a0 = xf[base + lane]      + xb[base + lane];
    float a1 = xf[base + 64 + lane] + xb[base + 64 + lane];
    float ss = a0 * a0 + a1 * a1;
    #pragma unroll
    for (int off = 32; off; off >>= 1) ss += __shfl_xor(ss, off);
    float r = rsqrtf(ss / 128.f + 1e-8f);
    xn[base + lane]      = a0 * r * w[lane];
    xn[base + 64 + lane] = a1 * r * w[64 + lane];
}

// ---------------------------------------------------------------------------
extern "C" void kernel_launch(void* const* d_in, const int* in_sizes, int n_in,
                              void* d_out, int out_size, void* d_ws, size_t ws_size,
                              hipStream_t stream)
{
    const float* x        = (const float*)d_in[0];
    const float* icw      = (const float*)d_in[1];
    const float* icb      = (const float*)d_in[2];
    const float* ocw      = (const float*)d_in[3];
    const float* ocb      = (const float*)d_in[4];
    const float* in_proj  = (const float*)d_in[5];
    const float* mconv_w  = (const float*)d_in[6];
    const float* mconv_b  = (const float*)d_in[7];
    const float* x_proj   = (const float*)d_in[8];
    const float* dt_w     = (const float*)d_in[9];
    const float* dt_b     = (const float*)d_in[10];
    const float* A_log    = (const float*)d_in[11];
    const float* Dp       = (const float*)d_in[12];
    const float* out_proj = (const float*)d_in[13];
    const float* norm_w   = (const float*)d_in[14];
    float* out = (float*)d_out;
    (void)in_sizes; (void)n_in; (void)out_size; (void)ws_size;

    float* w = (float*)d_ws;
    size_t off = 0;
    auto alloc = [&](size_t n) { float* p = w + off; off += n; return p; };
    float* p12   = alloc((size_t)4 * 1048576);  // conv partials; FREE during scan -> aliased as P
    float* xp    = alloc(1048576);
    float* xz    = alloc((size_t)HT * 512);
    float* xc_f  = alloc((size_t)HT * 256);
    float* xc_b  = alloc((size_t)HT * 256);
    float* dbc_f = alloc((size_t)HT * 264);
    float* dbc_b = alloc((size_t)HT * 264);
    float* del_f = alloc((size_t)HT * 256);
    float* del_b = alloc((size_t)HT * 256);
    float* ys_f  = alloc((size_t)HT * 256);
    float* ys_b  = alloc((size_t)HT * 256);
    float* xfo   = alloc((size_t)HT * 128);
    float* xbo   = alloc((size_t)HT * 128);
    float* xn    = alloc((size_t)HT * 128);
    float* QH    = alloc((size_t)8 * NCHUNK * 256 * 128);  // 4.19M floats
    float* P     = p12;                                     // alias (4.19M floats, exact fit)

    // 1) input conv (512x2048 out, K=128x128) + bias + silu
    conv_partial<512, 128, 4><<<dim3(8, 8, 4), 512, 0, stream>>>(x, icw, p12);
    conv_combine_silu<4><<<4096, 256, 0, stream>>>(p12, icb, xp, 512 * 2048);

    // 2) shared in_proj GEMM: xz = xp @ in_proj^T   (8192x512, K=128)
    gemm_nt<<<dim3(128, 8), 256, 0, stream>>>(xp, in_proj, xz, HT, 512, 128);

    // 3) depthwise conv + silu, both directions
    dwconv_silu<<<8192, 256, 0, stream>>>(xz, mconv_w, mconv_b, xc_f, 0);
    dwconv_silu<<<8192, 256, 0, stream>>>(xz, mconv_w, mconv_b, xc_b, 1);

    // 4) x_proj GEMMs: dbc = xc @ x_proj^T  (8192x264, K=256)
    gemm_nt<<<dim3(128, 5), 256, 0, stream>>>(xc_f, x_proj, dbc_f, HT, 264, 256);
    gemm_nt<<<dim3(128, 5), 256, 0, stream>>>(xc_b, x_proj, dbc_b, HT, 264, 256);

    // 5) delta = softplus(dt @ dt_w^T + dt_b)
    delta_softplus<<<8192, 256, 0, stream>>>(dbc_f, dt_w, dt_b, del_f);
    delta_softplus<<<8192, 256, 0, stream>>>(dbc_b, dt_w, dt_b, del_b);

    // 6) chunked selective scan, fwd+bwd
    scan_pass1<<<dim3(64, NCHUNK, 8), 256, 0, stream>>>(del_f, dbc_f, xc_f,
                                                        del_b, dbc_b, xc_b, A_log, P, QH);
    scan_pass2<<<1024, 256, 0, stream>>>(P, QH);
    scan_pass3<<<dim3(64, NCHUNK, 8), 256, 0, stream>>>(del_f, dbc_f, xc_f, ys_f,
                                                        del_b, dbc_b, xc_b, ys_b, A_log, QH);

    // 7) y = (ys + xc*D) * silu(z)  (in place)
    ycombine<<<8192, 256, 0, stream>>>(ys_f, xc_f, xz, Dp, ys_f);
    ycombine<<<8192, 256, 0, stream>>>(ys_b, xc_b, xz, Dp, ys_b);

    // 8) out_proj GEMMs (8192x128, K=256)
    gemm_nt<<<dim3(128, 2), 256, 0, stream>>>(ys_f, out_proj, xfo, HT, 128, 256);
    gemm_nt<<<dim3(128, 2), 256, 0, stream>>>(ys_b, out_proj, xbo, HT, 128, 256);

    // 9) rmsnorm(xf + xb)
    rmsnorm_add<<<2048, 256, 0, stream>>>(xfo, xbo, norm_w, xn);

    // 10) output conv (128x2048 out, K=512x128) + bias + silu -> d_out
    conv_partial<128, 512, 16><<<dim3(2, 8, 16), 512, 0, stream>>>(xn, ocw, p12);
    conv_combine_silu<16><<<1024, 256, 0, stream>>>(p12, ocb, out, 128 * 2048);
}

// Round 5
// 866.071 us; speedup vs baseline: 3.2368x; 2.5397x over previous
//
#include <hip/hip_runtime.h>
#include <math.h>
#include <cstddef>

// Problem constants (match reference)
#define SEQL   2048
#define DMODEL 128
#define NHEADS 4
#define DINNER 256
#define DSTATE 128
#define DTRANK 8
#define KWIDTH 128   // big conv kernel size
#define HT     (NHEADS*SEQL)   // 8192 rows for mamba GEMMs
#define NCHUNK 16
#define CHUNK  128   // SEQL / NCHUNK

typedef short bf16x8 __attribute__((ext_vector_type(8)));
typedef float f32x4  __attribute__((ext_vector_type(4)));
typedef unsigned short u16;

__device__ __forceinline__ u16 bf16rn(float f) {
    union { float f; unsigned u; } v; v.f = f;
    unsigned u = v.u + 0x7FFFu + ((v.u >> 16) & 1u);
    return (u16)(u >> 16);
}
__device__ __forceinline__ float bf16tof(u16 h) {
    union { unsigned u; float f; } v; v.u = ((unsigned)h) << 16;
    return v.f;
}

// ---------------------------------------------------------------------------
// Transpose + cast: in fp32 [R][C] -> out bf16 [C][R]. SPLIT: also write
// lo = bf16(x - float(hi)) for split-precision weights. R,C multiples of 32.
// ---------------------------------------------------------------------------
template<bool SPLIT>
__global__ __launch_bounds__(256)
void transpose_cast(const float* __restrict__ in, u16* __restrict__ outh,
                    u16* __restrict__ outl, int R, int C)
{
    __shared__ float T[32][33];
    const int r0 = blockIdx.y * 32, c0 = blockIdx.x * 32;
    {
        int ii = threadIdx.x >> 3, c4 = (threadIdx.x & 7) * 4;
        float4 v = *reinterpret_cast<const float4*>(in + (size_t)(r0 + ii) * C + c0 + c4);
        T[ii][c4 + 0] = v.x; T[ii][c4 + 1] = v.y; T[ii][c4 + 2] = v.z; T[ii][c4 + 3] = v.w;
    }
    __syncthreads();
    int cc = threadIdx.x >> 3, r4 = (threadIdx.x & 7) * 4;
    ushort4 h, l;
    float f0 = T[r4 + 0][cc], f1 = T[r4 + 1][cc], f2 = T[r4 + 2][cc], f3 = T[r4 + 3][cc];
    h.x = bf16rn(f0); h.y = bf16rn(f1); h.z = bf16rn(f2); h.w = bf16rn(f3);
    *reinterpret_cast<ushort4*>(outh + (size_t)(c0 + cc) * R + r0 + r4) = h;
    if (SPLIT) {
        l.x = bf16rn(f0 - bf16tof(h.x)); l.y = bf16rn(f1 - bf16tof(h.y));
        l.z = bf16rn(f2 - bf16tof(h.z)); l.w = bf16rn(f3 - bf16tof(h.w));
        *reinterpret_cast<ushort4*>(outl + (size_t)(c0 + cc) * R + r0 + r4) = l;
    }
}

// ---------------------------------------------------------------------------
// Big conv as per-tap implicit GEMM on MFMA.
// Xg: [2048][I_TOTAL] bf16 (transposed input). Wh/Wlo: [128][O_TOTAL*I_TOTAL]
// bf16 split weights, laid out Wt[k][o*I+i]. Yp: [KSPLIT][O_TOTAL][2048] fp32.
// Block: 128 o x 128 t, i-chunk = 32 (KSPLIT = I/32). 4 waves (2x2), each
// wave 64o x 64t = 4x4 fragments of 16x16. K-loop over 128 taps, 2/iter.
// y[o,t] = sum_k sum_i W[k][o][i] * Xg[t+k-63][i]
// ---------------------------------------------------------------------------
template<int O_TOTAL, int I_TOTAL>
__global__ __launch_bounds__(256)
void conv_mfma(const u16* __restrict__ Xg, const u16* __restrict__ Wh,
               const u16* __restrict__ Wlo, float* __restrict__ Yp)
{
    __shared__ u16 Xt[256][32];        // rows p = t0-63+r
    __shared__ u16 Ws[4][128][32];     // [kl*2+hl][o][i]
    const int tid = threadIdx.x;
    const int lane = tid & 63;
    const int wid = tid >> 6;
    const int wo = wid >> 1, wt = wid & 1;
    const int o0 = blockIdx.x * 128;
    const int i0 = blockIdx.y * 32;
    const int t0 = blockIdx.z * 128;
    const int l15 = lane & 15, l4 = lane >> 4;

    // stage X tile once (rows 0..255 <-> p = t0-63+row)
    #pragma unroll
    for (int it = 0; it < 4; ++it) {
        int e = it * 2048 + tid * 8;
        int r = e >> 5, col = e & 31;
        int p = t0 - 63 + r;
        bf16x8 v = {};
        if (p >= 0 && p < 2048)
            v = *reinterpret_cast<const bf16x8*>(Xg + (size_t)p * I_TOTAL + i0 + col);
        *reinterpret_cast<bf16x8*>(&Xt[r][col]) = v;
    }

    f32x4 acc[4][4];
    #pragma unroll
    for (int a = 0; a < 4; ++a)
        #pragma unroll
        for (int b = 0; b < 4; ++b) acc[a][b] = (f32x4){0.f, 0.f, 0.f, 0.f};

    const size_t wstride = (size_t)O_TOTAL * I_TOTAL;
    bf16x8 wreg[8];
    // prologue: load taps 0,1 (hi+lo)
    #pragma unroll
    for (int it = 0; it < 8; ++it) {
        int e = it * 2048 + tid * 8;
        int s = e >> 12; int kloc = s >> 1, hl = s & 1;
        const u16* src = hl ? Wlo : Wh;
        wreg[it] = *reinterpret_cast<const bf16x8*>(
            src + (size_t)kloc * wstride + (size_t)(o0 + ((e >> 5) & 127)) * I_TOTAL + i0 + (e & 31));
    }

    for (int tp = 0; tp < 64; ++tp) {
        __syncthreads();   // previous compute done; safe to overwrite Ws
        #pragma unroll
        for (int it = 0; it < 8; ++it) {
            int e = it * 2048 + tid * 8;
            *reinterpret_cast<bf16x8*>(&Ws[e >> 12][(e >> 5) & 127][e & 31]) = wreg[it];
        }
        if (tp + 1 < 64) {
            int k0n = (tp + 1) * 2;
            #pragma unroll
            for (int it = 0; it < 8; ++it) {
                int e = it * 2048 + tid * 8;
                int s = e >> 12; int kloc = s >> 1, hl = s & 1;
                const u16* src = hl ? Wlo : Wh;
                wreg[it] = *reinterpret_cast<const bf16x8*>(
                    src + (size_t)(k0n + kloc) * wstride + (size_t)(o0 + ((e >> 5) & 127)) * I_TOTAL + i0 + (e & 31));
            }
        }
        __syncthreads();
        #pragma unroll
        for (int kl = 0; kl < 2; ++kl) {
            const int k = tp * 2 + kl;
            bf16x8 B[4];
            #pragma unroll
            for (int b = 0; b < 4; ++b) {
                int row = wt * 64 + b * 16 + l15 + k;
                B[b] = *reinterpret_cast<const bf16x8*>(&Xt[row][l4 * 8]);
            }
            #pragma unroll
            for (int hl = 0; hl < 2; ++hl) {
                #pragma unroll
                for (int a = 0; a < 4; ++a) {
                    bf16x8 A = *reinterpret_cast<const bf16x8*>(
                        &Ws[kl * 2 + hl][wo * 64 + a * 16 + l15][l4 * 8]);
                    #pragma unroll
                    for (int b = 0; b < 4; ++b)
                        acc[a][b] = __builtin_amdgcn_mfma_f32_16x16x32_bf16(A, B[b], acc[a][b], 0, 0, 0);
                }
            }
        }
    }

    float* outp = Yp + (size_t)blockIdx.y * ((size_t)O_TOTAL * 2048);
    #pragma unroll
    for (int a = 0; a < 4; ++a)
        #pragma unroll
        for (int b = 0; b < 4; ++b) {
            int col = t0 + wt * 64 + b * 16 + l15;
            #pragma unroll
            for (int r = 0; r < 4; ++r) {
                int row = o0 + wo * 64 + a * 16 + l4 * 4 + r;
                outp[(size_t)row * 2048 + col] = acc[a][b][r];
            }
        }
}

// combine K-split partials + bias + silu
template<int KSPLIT>
__global__ void conv_combine_silu(const float* __restrict__ Yp, const float* __restrict__ bias,
                                  float* __restrict__ out, int total)
{
    int f = blockIdx.x * 256 + threadIdx.x;
    if (f >= total) return;
    float s = bias[f >> 11];
    #pragma unroll
    for (int z = 0; z < KSPLIT; ++z) s += Yp[(size_t)z * total + f];
    out[f] = s / (1.f + __expf(-s));
}

// ---------------------------------------------------------------------------
// Generic fp32 GEMM, C[M][N] = A[M][K] * B[N][K]^T
// ---------------------------------------------------------------------------
__global__ __launch_bounds__(256)
void gemm_nt(const float* __restrict__ A, const float* __restrict__ B,
             float* __restrict__ C, int M, int N, int K)
{
    constexpr int BM = 64, BN = 64, BK = 16;
    __shared__ __align__(16) float As[BK][BM + 4];
    __shared__ __align__(16) float Bs[BK][BN + 4];
    const int m0 = blockIdx.x * BM, n0 = blockIdx.y * BN;
    const int tid = threadIdx.x;
    const int ty = tid >> 4, tx = tid & 15;
    float acc[4][4] = {};

    for (int k0 = 0; k0 < K; k0 += BK) {
        __syncthreads();
        {
            int r  = tid >> 2;
            int kb = (tid & 3) * 4;
            float4 va = *reinterpret_cast<const float4*>(A + (size_t)(m0 + r) * K + k0 + kb);
            As[kb+0][r] = va.x; As[kb+1][r] = va.y; As[kb+2][r] = va.z; As[kb+3][r] = va.w;
            float4 vb = make_float4(0.f, 0.f, 0.f, 0.f);
            if (n0 + r < N)
                vb = *reinterpret_cast<const float4*>(B + (size_t)(n0 + r) * K + k0 + kb);
            Bs[kb+0][r] = vb.x; Bs[kb+1][r] = vb.y; Bs[kb+2][r] = vb.z; Bs[kb+3][r] = vb.w;
        }
        __syncthreads();
        #pragma unroll
        for (int k = 0; k < BK; ++k) {
            float4 a4 = *reinterpret_cast<const float4*>(&As[k][ty * 4]);
            float4 b4 = *reinterpret_cast<const float4*>(&Bs[k][tx * 4]);
            float av[4] = {a4.x, a4.y, a4.z, a4.w};
            float bv[4] = {b4.x, b4.y, b4.z, b4.w};
            #pragma unroll
            for (int i = 0; i < 4; ++i)
                #pragma unroll
                for (int j = 0; j < 4; ++j) acc[i][j] += av[i] * bv[j];
        }
    }
    #pragma unroll
    for (int i = 0; i < 4; ++i) {
        int m = m0 + ty * 4 + i;
        #pragma unroll
        for (int j = 0; j < 4; ++j) {
            int n = n0 + tx * 4 + j;
            if (n < N) C[(size_t)m * N + n] = acc[i][j];
        }
    }
}

// ---------------------------------------------------------------------------
// depthwise conv (7 taps) + silu
// ---------------------------------------------------------------------------
__global__ void dwconv_silu(const float* __restrict__ xz, const float* __restrict__ w7,
                            const float* __restrict__ cb, float* __restrict__ xc, int dir)
{
    int idx = blockIdx.x * 256 + threadIdx.x;
    if (idx >= HT * 256) return;
    int c = idx & 255;
    int ht = idx >> 8;
    int h = ht >> 11, t = ht & 2047;
    float s = cb[c];
    #pragma unroll
    for (int k = 0; k < 7; ++k) {
        int tt = dir ? (t + 6 - k) : (t - 6 + k);
        if (tt >= 0 && tt < SEQL)
            s += w7[c * 7 + k] * xz[((size_t)(h << 11) + tt) * 512 + c];
    }
    xc[idx] = s / (1.f + __expf(-s));
}

__global__ void delta_softplus(const float* __restrict__ dbc, const float* __restrict__ dtw,
                               const float* __restrict__ dtb, float* __restrict__ delta)
{
    int idx = blockIdx.x * 256 + threadIdx.x;
    if (idx >= HT * 256) return;
    int c = idx & 255;
    int ht = idx >> 8;
    const float* dr = dbc + (size_t)ht * 264;
    float s = dtb[c];
    #pragma unroll
    for (int r = 0; r < 8; ++r) s += dr[r] * dtw[c * 8 + r];
    delta[idx] = (s > 20.f) ? s : log1pf(__expf(s));
}

// ---------------------------------------------------------------------------
// Chunked selective scan (3 passes). See round-2 notes.
// P/Q layout: [dirh(8)][chunk(16)][d(256)][n(128)]
// ---------------------------------------------------------------------------
__global__ __launch_bounds__(256)
void scan_pass1(const float* __restrict__ del_f, const float* __restrict__ dbc_f,
                const float* __restrict__ xc_f,
                const float* __restrict__ del_b, const float* __restrict__ dbc_b,
                const float* __restrict__ xc_b,
                const float* __restrict__ A_log, float* __restrict__ P, float* __restrict__ Q)
{
    const int wid = threadIdx.x >> 6, lane = threadIdx.x & 63;
    const int d  = blockIdx.x * 4 + wid;
    const int c  = blockIdx.y;
    const int hd = blockIdx.z;
    const int dir = hd >> 2, h = hd & 3;
    const float* del = dir ? del_b : del_f;
    const float* dbc = dir ? dbc_b : dbc_f;
    const float* xc  = dir ? xc_b  : xc_f;

    const float A0 = -__expf(A_log[d * 128 + lane]);
    const float A1 = -__expf(A_log[d * 128 + 64 + lane]);
    float h0 = 0.f, h1 = 0.f, p0 = 1.f, p1 = 1.f;

    for (int s = 0; s < CHUNK; ++s) {
        int g = c * CHUNK + s;
        int t = dir ? (2047 - g) : g;
        size_t ht = (size_t)h * 2048 + t;
        float dlt = del[ht * 256 + d];
        float u   = xc[ht * 256 + d];
        const float* pp = dbc + ht * 264;
        float B0 = pp[8 + lane], B1 = pp[72 + lane];
        float du = dlt * u;
        float a0 = __expf(dlt * A0), a1 = __expf(dlt * A1);
        h0 = a0 * h0 + du * B0;
        h1 = a1 * h1 + du * B1;
        p0 *= a0; p1 *= a1;
    }
    size_t base = (((size_t)hd * NCHUNK + c) * 256 + d) * 128;
    P[base + lane] = p0;  P[base + 64 + lane] = p1;
    Q[base + lane] = h0;  Q[base + 64 + lane] = h1;
}

__global__ void scan_pass2(const float* __restrict__ P, float* __restrict__ Q)
{
    int idx = blockIdx.x * 256 + threadIdx.x;   // 262144
    int hd = idx >> 15;
    int dn = idx & 32767;
    size_t b0 = (size_t)hd * NCHUNK * 32768 + dn;
    float hcur = 0.f;
    for (int c = 0; c < NCHUNK; ++c) {
        size_t o = b0 + (size_t)c * 32768;
        float q = Q[o];
        Q[o] = hcur;
        hcur = P[o] * hcur + q;
    }
}

__global__ __launch_bounds__(256)
void scan_pass3(const float* __restrict__ del_f, const float* __restrict__ dbc_f,
                const float* __restrict__ xc_f, float* __restrict__ ys_f,
                const float* __restrict__ del_b, const float* __restrict__ dbc_b,
                const float* __restrict__ xc_b, float* __restrict__ ys_b,
                const float* __restrict__ A_log, const float* __restrict__ H)
{
    const int wid = threadIdx.x >> 6, lane = threadIdx.x & 63;
    const int d  = blockIdx.x * 4 + wid;
    const int c  = blockIdx.y;
    const int hd = blockIdx.z;
    const int dir = hd >> 2, h = hd & 3;
    const float* del = dir ? del_b : del_f;
    const float* dbc = dir ? dbc_b : dbc_f;
    const float* xc  = dir ? xc_b  : xc_f;
    float* ys        = dir ? ys_b  : ys_f;

    const float A0 = -__expf(A_log[d * 128 + lane]);
    const float A1 = -__expf(A_log[d * 128 + 64 + lane]);
    size_t base = (((size_t)hd * NCHUNK + c) * 256 + d) * 128;
    float h0 = H[base + lane], h1 = H[base + 64 + lane];

    for (int s = 0; s < CHUNK; ++s) {
        int g = c * CHUNK + s;
        int t = dir ? (2047 - g) : g;
        size_t ht = (size_t)h * 2048 + t;
        float dlt = del[ht * 256 + d];
        float u   = xc[ht * 256 + d];
        const float* pp = dbc + ht * 264;
        float B0 = pp[8 + lane],   B1 = pp[72 + lane];
        float C0 = pp[136 + lane], C1 = pp[200 + lane];
        float du = dlt * u;
        h0 = __expf(dlt * A0) * h0 + du * B0;
        h1 = __expf(dlt * A1) * h1 + du * B1;
        float v = h0 * C0 + h1 * C1;
        #pragma unroll
        for (int off = 32; off; off >>= 1) v += __shfl_down(v, off);
        if (lane == 0) ys[ht * 256 + d] = v;
    }
}

__global__ void ycombine(const float* ysin, const float* __restrict__ xc,
                         const float* __restrict__ xz, const float* __restrict__ Dp,
                         float* yout)
{
    int idx = blockIdx.x * 256 + threadIdx.x;
    if (idx >= HT * 256) return;
    int c = idx & 255;
    size_t ht = idx >> 8;
    float z = xz[ht * 512 + 256 + c];
    float y = (ysin[idx] + xc[idx] * Dp[c]) * (z / (1.f + __expf(-z)));
    yout[idx] = y;
}

__global__ __launch_bounds__(256)
void rmsnorm_add(const float* __restrict__ xf, const float* __restrict__ xb,
                 const float* __restrict__ w, float* __restrict__ xn)
{
    int row  = blockIdx.x * 4 + (threadIdx.x >> 6);
    int lane = threadIdx.x & 63;
    size_t base = (size_t)row * 128;
    float a0 = xf[base + lane]      + xb[base + lane];
    float a1 = xf[base + 64 + lane] + xb[base + 64 + lane];
    float ss = a0 * a0 + a1 * a1;
    #pragma unroll
    for (int off = 32; off; off >>= 1) ss += __shfl_xor(ss, off);
    float r = rsqrtf(ss / 128.f + 1e-8f);
    xn[base + lane]      = a0 * r * w[lane];
    xn[base + 64 + lane] = a1 * r * w[64 + lane];
}

// ---------------------------------------------------------------------------
extern "C" void kernel_launch(void* const* d_in, const int* in_sizes, int n_in,
                              void* d_out, int out_size, void* d_ws, size_t ws_size,
                              hipStream_t stream)
{
    const float* x        = (const float*)d_in[0];
    const float* icw      = (const float*)d_in[1];
    const float* icb      = (const float*)d_in[2];
    const float* ocw      = (const float*)d_in[3];
    const float* ocb      = (const float*)d_in[4];
    const float* in_proj  = (const float*)d_in[5];
    const float* mconv_w  = (const float*)d_in[6];
    const float* mconv_b  = (const float*)d_in[7];
    const float* x_proj   = (const float*)d_in[8];
    const float* dt_w     = (const float*)d_in[9];
    const float* dt_b     = (const float*)d_in[10];
    const float* A_log    = (const float*)d_in[11];
    const float* Dp       = (const float*)d_in[12];
    const float* out_proj = (const float*)d_in[13];
    const float* norm_w   = (const float*)d_in[14];
    float* out = (float*)d_out;
    (void)in_sizes; (void)n_in; (void)out_size; (void)ws_size;

    float* w = (float*)d_ws;
    size_t off = 0;
    auto alloc = [&](size_t n) { float* p = w + off; off += n; return p; };
    float* p12   = alloc((size_t)4 * 1048576);  // conv1 partials; P (scan); W2lo alias
    float* xp    = alloc(1048576);
    float* xz    = alloc((size_t)HT * 512);     // also aliased: Wt1h (before step 2)
    float* xc_f  = alloc((size_t)HT * 256);     // also aliased: Wt1l (before step 3), xn2t (after step 7)
    float* xc_b  = alloc((size_t)HT * 256);
    float* dbc_f = alloc((size_t)HT * 264);
    float* dbc_b = alloc((size_t)HT * 264);
    float* del_f = alloc((size_t)HT * 256);
    float* del_b = alloc((size_t)HT * 256);
    float* ys_f  = alloc((size_t)HT * 256);     // ys_f+ys_b reused as conv2 partials
    float* ys_b  = alloc((size_t)HT * 256);
    float* xfo   = alloc((size_t)HT * 128);     // also aliased: xb1t (before step 8)
    float* xbo   = alloc((size_t)HT * 128);
    float* xn    = alloc((size_t)HT * 128);
    float* QH    = alloc((size_t)8 * NCHUNK * 256 * 128);  // scan Q; W2h alias after

    // bf16 aliases (disjoint lifetimes, see comments)
    u16* Wt1h = (u16*)xz;     // 8.39M elems = 16.8MB <= xz (16.8MB); dead before step 2
    u16* Wt1l = (u16*)xc_f;   // 16.8MB spans xc_f+xc_b; dead before step 3
    u16* xb1t = (u16*)xfo;    // 0.5MB; dead before step 8
    u16* W2h  = (u16*)QH;     // written after scan (QH dead)
    u16* W2l  = (u16*)p12;    // written after scan (P dead)
    u16* xn2t = (u16*)xc_f;   // written after ycombine (xc dead)
    float* cp2 = ys_f;        // conv2 partials: 16 x 262144 floats = ys_f+ys_b

    // 0) transposed bf16 weights/inputs for conv1
    transpose_cast<true><<<dim3(4, 2048), 256, 0, stream>>>(icw, Wt1h, Wt1l, 512 * 128, 128);
    transpose_cast<false><<<dim3(64, 4), 256, 0, stream>>>(x, xb1t, nullptr, 128, 2048);

    // 1) input conv via MFMA (KSPLIT=4) + bias + silu
    conv_mfma<512, 128><<<dim3(4, 4, 16), 256, 0, stream>>>(xb1t, Wt1h, Wt1l, p12);
    conv_combine_silu<4><<<4096, 256, 0, stream>>>(p12, icb, xp, 512 * 2048);

    // 2) shared in_proj GEMM: xz = xp @ in_proj^T   (8192x512, K=128)
    gemm_nt<<<dim3(128, 8), 256, 0, stream>>>(xp, in_proj, xz, HT, 512, 128);

    // 3) depthwise conv + silu, both directions
    dwconv_silu<<<8192, 256, 0, stream>>>(xz, mconv_w, mconv_b, xc_f, 0);
    dwconv_silu<<<8192, 256, 0, stream>>>(xz, mconv_w, mconv_b, xc_b, 1);

    // 4) x_proj GEMMs: dbc = xc @ x_proj^T  (8192x264, K=256)
    gemm_nt<<<dim3(128, 5), 256, 0, stream>>>(xc_f, x_proj, dbc_f, HT, 264, 256);
    gemm_nt<<<dim3(128, 5), 256, 0, stream>>>(xc_b, x_proj, dbc_b, HT, 264, 256);

    // 5) delta = softplus(dt @ dt_w^T + dt_b)
    delta_softplus<<<8192, 256, 0, stream>>>(dbc_f, dt_w, dt_b, del_f);
    delta_softplus<<<8192, 256, 0, stream>>>(dbc_b, dt_w, dt_b, del_b);

    // 6) chunked selective scan, fwd+bwd
    scan_pass1<<<dim3(64, NCHUNK, 8), 256, 0, stream>>>(del_f, dbc_f, xc_f,
                                                        del_b, dbc_b, xc_b, A_log, p12, QH);
    scan_pass2<<<1024, 256, 0, stream>>>(p12, QH);
    scan_pass3<<<dim3(64, NCHUNK, 8), 256, 0, stream>>>(del_f, dbc_f, xc_f, ys_f,
                                                        del_b, dbc_b, xc_b, ys_b, A_log, QH);

    // 7) y = (ys + xc*D) * silu(z)  (in place)
    ycombine<<<8192, 256, 0, stream>>>(ys_f, xc_f, xz, Dp, ys_f);
    ycombine<<<8192, 256, 0, stream>>>(ys_b, xc_b, xz, Dp, ys_b);

    // 8) out_proj GEMMs (8192x128, K=256)
    gemm_nt<<<dim3(128, 2), 256, 0, stream>>>(ys_f, out_proj, xfo, HT, 128, 256);
    gemm_nt<<<dim3(128, 2), 256, 0, stream>>>(ys_b, out_proj, xbo, HT, 128, 256);

    // 9) rmsnorm(xf + xb)
    rmsnorm_add<<<2048, 256, 0, stream>>>(xfo, xbo, norm_w, xn);

    // 9.5) transposed bf16 for conv2 (xn is [512][2048] flat-channel view)
    transpose_cast<false><<<dim3(64, 16), 256, 0, stream>>>(xn, xn2t, nullptr, 512, 2048);
    transpose_cast<true><<<dim3(4, 2048), 256, 0, stream>>>(ocw, W2h, W2l, 128 * 512, 128);

    // 10) output conv via MFMA (KSPLIT=16) + bias + silu -> d_out
    conv_mfma<128, 512><<<dim3(1, 16, 16), 256, 0, stream>>>(xn2t, W2h, W2l, cp2);
    conv_combine_silu<16><<<1024, 256, 0, stream>>>(cp2, ocb, out, 128 * 2048);
}

// Round 6
// 639.819 us; speedup vs baseline: 4.3814x; 1.3536x over previous
//
#include <hip/hip_runtime.h>
#include <math.h>
#include <cstddef>

// Problem constants (match reference)
#define SEQL   2048
#define DMODEL 128
#define NHEADS 4
#define DINNER 256
#define DSTATE 128
#define DTRANK 8
#define KWIDTH 128   // big conv kernel size
#define HT     (NHEADS*SEQL)   // 8192 rows for mamba GEMMs

typedef short bf16x8 __attribute__((ext_vector_type(8)));
typedef float f32x4  __attribute__((ext_vector_type(4)));
typedef unsigned short u16;

__device__ __forceinline__ u16 bf16rn(float f) {
    union { float f; unsigned u; } v; v.f = f;
    unsigned u = v.u + 0x7FFFu + ((v.u >> 16) & 1u);
    return (u16)(u >> 16);
}
__device__ __forceinline__ float bf16tof(u16 h) {
    union { unsigned u; float f; } v; v.u = ((unsigned)h) << 16;
    return v.f;
}

// ---------------------------------------------------------------------------
// Transpose + cast: in fp32 [R][C] -> out bf16 [C][R]. SPLIT: also write
// lo = bf16(x - float(hi)) for split-precision weights. R,C multiples of 32.
// ---------------------------------------------------------------------------
template<bool SPLIT>
__global__ __launch_bounds__(256)
void transpose_cast(const float* __restrict__ in, u16* __restrict__ outh,
                    u16* __restrict__ outl, int R, int C)
{
    __shared__ float T[32][33];
    const int r0 = blockIdx.y * 32, c0 = blockIdx.x * 32;
    {
        int ii = threadIdx.x >> 3, c4 = (threadIdx.x & 7) * 4;
        float4 v = *reinterpret_cast<const float4*>(in + (size_t)(r0 + ii) * C + c0 + c4);
        T[ii][c4 + 0] = v.x; T[ii][c4 + 1] = v.y; T[ii][c4 + 2] = v.z; T[ii][c4 + 3] = v.w;
    }
    __syncthreads();
    int cc = threadIdx.x >> 3, r4 = (threadIdx.x & 7) * 4;
    ushort4 h, l;
    float f0 = T[r4 + 0][cc], f1 = T[r4 + 1][cc], f2 = T[r4 + 2][cc], f3 = T[r4 + 3][cc];
    h.x = bf16rn(f0); h.y = bf16rn(f1); h.z = bf16rn(f2); h.w = bf16rn(f3);
    *reinterpret_cast<ushort4*>(outh + (size_t)(c0 + cc) * R + r0 + r4) = h;
    if (SPLIT) {
        l.x = bf16rn(f0 - bf16tof(h.x)); l.y = bf16rn(f1 - bf16tof(h.y));
        l.z = bf16rn(f2 - bf16tof(h.z)); l.w = bf16rn(f3 - bf16tof(h.w));
        *reinterpret_cast<ushort4*>(outl + (size_t)(c0 + cc) * R + r0 + r4) = l;
    }
}

// ---------------------------------------------------------------------------
// Big conv as per-tap implicit GEMM on MFMA (see round-3 notes).
// ---------------------------------------------------------------------------
template<int O_TOTAL, int I_TOTAL>
__global__ __launch_bounds__(256)
void conv_mfma(const u16* __restrict__ Xg, const u16* __restrict__ Wh,
               const u16* __restrict__ Wlo, float* __restrict__ Yp)
{
    __shared__ u16 Xt[256][32];        // rows p = t0-63+r
    __shared__ u16 Ws[4][128][32];     // [kl*2+hl][o][i]
    const int tid = threadIdx.x;
    const int lane = tid & 63;
    const int wid = tid >> 6;
    const int wo = wid >> 1, wt = wid & 1;
    const int o0 = blockIdx.x * 128;
    const int i0 = blockIdx.y * 32;
    const int t0 = blockIdx.z * 128;
    const int l15 = lane & 15, l4 = lane >> 4;

    #pragma unroll
    for (int it = 0; it < 4; ++it) {
        int e = it * 2048 + tid * 8;
        int r = e >> 5, col = e & 31;
        int p = t0 - 63 + r;
        bf16x8 v = {};
        if (p >= 0 && p < 2048)
            v = *reinterpret_cast<const bf16x8*>(Xg + (size_t)p * I_TOTAL + i0 + col);
        *reinterpret_cast<bf16x8*>(&Xt[r][col]) = v;
    }

    f32x4 acc[4][4];
    #pragma unroll
    for (int a = 0; a < 4; ++a)
        #pragma unroll
        for (int b = 0; b < 4; ++b) acc[a][b] = (f32x4){0.f, 0.f, 0.f, 0.f};

    const size_t wstride = (size_t)O_TOTAL * I_TOTAL;
    bf16x8 wreg[8];
    #pragma unroll
    for (int it = 0; it < 8; ++it) {
        int e = it * 2048 + tid * 8;
        int s = e >> 12; int kloc = s >> 1, hl = s & 1;
        const u16* src = hl ? Wlo : Wh;
        wreg[it] = *reinterpret_cast<const bf16x8*>(
            src + (size_t)kloc * wstride + (size_t)(o0 + ((e >> 5) & 127)) * I_TOTAL + i0 + (e & 31));
    }

    for (int tp = 0; tp < 64; ++tp) {
        __syncthreads();
        #pragma unroll
        for (int it = 0; it < 8; ++it) {
            int e = it * 2048 + tid * 8;
            *reinterpret_cast<bf16x8*>(&Ws[e >> 12][(e >> 5) & 127][e & 31]) = wreg[it];
        }
        if (tp + 1 < 64) {
            int k0n = (tp + 1) * 2;
            #pragma unroll
            for (int it = 0; it < 8; ++it) {
                int e = it * 2048 + tid * 8;
                int s = e >> 12; int kloc = s >> 1, hl = s & 1;
                const u16* src = hl ? Wlo : Wh;
                wreg[it] = *reinterpret_cast<const bf16x8*>(
                    src + (size_t)(k0n + kloc) * wstride + (size_t)(o0 + ((e >> 5) & 127)) * I_TOTAL + i0 + (e & 31));
            }
        }
        __syncthreads();
        #pragma unroll
        for (int kl = 0; kl < 2; ++kl) {
            const int k = tp * 2 + kl;
            bf16x8 B[4];
            #pragma unroll
            for (int b = 0; b < 4; ++b) {
                int row = wt * 64 + b * 16 + l15 + k;
                B[b] = *reinterpret_cast<const bf16x8*>(&Xt[row][l4 * 8]);
            }
            #pragma unroll
            for (int hl = 0; hl < 2; ++hl) {
                #pragma unroll
                for (int a = 0; a < 4; ++a) {
                    bf16x8 A = *reinterpret_cast<const bf16x8*>(
                        &Ws[kl * 2 + hl][wo * 64 + a * 16 + l15][l4 * 8]);
                    #pragma unroll
                    for (int b = 0; b < 4; ++b)
                        acc[a][b] = __builtin_amdgcn_mfma_f32_16x16x32_bf16(A, B[b], acc[a][b], 0, 0, 0);
                }
            }
        }
    }

    float* outp = Yp + (size_t)blockIdx.y * ((size_t)O_TOTAL * 2048);
    #pragma unroll
    for (int a = 0; a < 4; ++a)
        #pragma unroll
        for (int b = 0; b < 4; ++b) {
            int col = t0 + wt * 64 + b * 16 + l15;
            #pragma unroll
            for (int r = 0; r < 4; ++r) {
                int row = o0 + wo * 64 + a * 16 + l4 * 4 + r;
                outp[(size_t)row * 2048 + col] = acc[a][b][r];
            }
        }
}

template<int KSPLIT>
__global__ void conv_combine_silu(const float* __restrict__ Yp, const float* __restrict__ bias,
                                  float* __restrict__ out, int total)
{
    int f = blockIdx.x * 256 + threadIdx.x;
    if (f >= total) return;
    float s = bias[f >> 11];
    #pragma unroll
    for (int z = 0; z < KSPLIT; ++z) s += Yp[(size_t)z * total + f];
    out[f] = s / (1.f + __expf(-s));
}

// ---------------------------------------------------------------------------
// Generic fp32 GEMM, C[M][N] = A[M][K] * B[N][K]^T
// ---------------------------------------------------------------------------
__global__ __launch_bounds__(256)
void gemm_nt(const float* __restrict__ A, const float* __restrict__ B,
             float* __restrict__ C, int M, int N, int K)
{
    constexpr int BM = 64, BN = 64, BK = 16;
    __shared__ __align__(16) float As[BK][BM + 4];
    __shared__ __align__(16) float Bs[BK][BN + 4];
    const int m0 = blockIdx.x * BM, n0 = blockIdx.y * BN;
    const int tid = threadIdx.x;
    const int ty = tid >> 4, tx = tid & 15;
    float acc[4][4] = {};

    for (int k0 = 0; k0 < K; k0 += BK) {
        __syncthreads();
        {
            int r  = tid >> 2;
            int kb = (tid & 3) * 4;
            float4 va = *reinterpret_cast<const float4*>(A + (size_t)(m0 + r) * K + k0 + kb);
            As[kb+0][r] = va.x; As[kb+1][r] = va.y; As[kb+2][r] = va.z; As[kb+3][r] = va.w;
            float4 vb = make_float4(0.f, 0.f, 0.f, 0.f);
            if (n0 + r < N)
                vb = *reinterpret_cast<const float4*>(B + (size_t)(n0 + r) * K + k0 + kb);
            Bs[kb+0][r] = vb.x; Bs[kb+1][r] = vb.y; Bs[kb+2][r] = vb.z; Bs[kb+3][r] = vb.w;
        }
        __syncthreads();
        #pragma unroll
        for (int k = 0; k < BK; ++k) {
            float4 a4 = *reinterpret_cast<const float4*>(&As[k][ty * 4]);
            float4 b4 = *reinterpret_cast<const float4*>(&Bs[k][tx * 4]);
            float av[4] = {a4.x, a4.y, a4.z, a4.w};
            float bv[4] = {b4.x, b4.y, b4.z, b4.w};
            #pragma unroll
            for (int i = 0; i < 4; ++i)
                #pragma unroll
                for (int j = 0; j < 4; ++j) acc[i][j] += av[i] * bv[j];
        }
    }
    #pragma unroll
    for (int i = 0; i < 4; ++i) {
        int m = m0 + ty * 4 + i;
        #pragma unroll
        for (int j = 0; j < 4; ++j) {
            int n = n0 + tx * 4 + j;
            if (n < N) C[(size_t)m * N + n] = acc[i][j];
        }
    }
}

// ---------------------------------------------------------------------------
// depthwise conv (7 taps) + silu
// ---------------------------------------------------------------------------
__global__ void dwconv_silu(const float* __restrict__ xz, const float* __restrict__ w7,
                            const float* __restrict__ cb, float* __restrict__ xc, int dir)
{
    int idx = blockIdx.x * 256 + threadIdx.x;
    if (idx >= HT * 256) return;
    int c = idx & 255;
    int ht = idx >> 8;
    int h = ht >> 11, t = ht & 2047;
    float s = cb[c];
    #pragma unroll
    for (int k = 0; k < 7; ++k) {
        int tt = dir ? (t + 6 - k) : (t - 6 + k);
        if (tt >= 0 && tt < SEQL)
            s += w7[c * 7 + k] * xz[((size_t)(h << 11) + tt) * 512 + c];
    }
    xc[idx] = s / (1.f + __expf(-s));
}

__global__ void delta_softplus(const float* __restrict__ dbc, const float* __restrict__ dtw,
                               const float* __restrict__ dtb, float* __restrict__ delta)
{
    int idx = blockIdx.x * 256 + threadIdx.x;
    if (idx >= HT * 256) return;
    int c = idx & 255;
    int ht = idx >> 8;
    const float* dr = dbc + (size_t)ht * 264;
    float s = dtb[c];
    #pragma unroll
    for (int r = 0; r < 8; ++r) s += dr[r] * dtw[c * 8 + r];
    delta[idx] = (s > 20.f) ? s : log1pf(__expf(s));
}

// ---------------------------------------------------------------------------
// Chunked selective scan, lane-=d layout.
// Per (dir,h,d,n): h_t = exp(delta_t,d*A_d,n)*h_{t-1} + delta_t,d*u_t,d*B_t,n
// y_t,d = sum_n h_t,d,n*C_t,n ; scan order g: fwd t=g, bwd t=2047-g.
// An[n*256+d] = -exp(A_log[d*128+n])  (precomputed, coalesced for lane=d).
// Q layout: [hd(8)][chunk(NC)][n(128)][d(256)]; S: [hd][chunk][d] = sum delta.
// pass1: local chunk scan from 0 -> Q (end state) + S. No P needed:
//        cumprod = exp(A * S) (exp-of-sum trick).
// pass2: thread per (hd,n,d): sequential chunk combine; Q <- chunk-START state.
// pass3: rescan from true start state, y accumulated per-lane over the serial
//        n-loop (no shuffles); both n-halves combine via 2-writer atomicAdd
//        onto zeroed ys (commutative -> deterministic).
// Block: 256 thr = 4 waves (wave w -> d = w*64+lane); grid (nhalf=2, NC, hd=8).
// B/C staged in LDS per 64-step segment (one barrier/segment).
// ---------------------------------------------------------------------------
template<int NC>
__global__ __launch_bounds__(256)
void scan_pass1(const float* __restrict__ del_f, const float* __restrict__ dbc_f,
                const float* __restrict__ xc_f,
                const float* __restrict__ del_b, const float* __restrict__ dbc_b,
                const float* __restrict__ xc_b,
                const float* __restrict__ An, float* __restrict__ Q, float* __restrict__ S)
{
    constexpr int CH = 2048 / NC;
    __shared__ float Bs[64][64];
    const int tid = threadIdx.x, lane = tid & 63, wv = tid >> 6;
    const int nh = blockIdx.x, c = blockIdx.y, hd = blockIdx.z;
    const int dir = hd >> 2, h = hd & 3;
    const int n0 = nh * 64, d = wv * 64 + lane;
    const float* del = dir ? del_b : del_f;
    const float* dbc = dir ? dbc_b : dbc_f;
    const float* xc  = dir ? xc_b  : xc_f;

    float A[64], hreg[64];
    #pragma unroll
    for (int j = 0; j < 64; ++j) { A[j] = An[(size_t)(n0 + j) * 256 + d]; hreg[j] = 0.f; }
    float sS = 0.f;

    for (int seg = 0; seg < CH / 64; ++seg) {
        __syncthreads();
        for (int e = tid; e < 64 * 64; e += 256) {
            int t = e >> 6, j = e & 63;
            int g = c * CH + seg * 64 + t;
            int tt = dir ? 2047 - g : g;
            Bs[t][j] = dbc[((size_t)h * 2048 + tt) * 264 + 8 + n0 + j];
        }
        __syncthreads();

        int g0 = c * CH + seg * 64;
        int tt0 = dir ? 2047 - g0 : g0;
        size_t htc = (size_t)h * 2048 + tt0;
        float dlt = del[htc * 256 + d];
        float u   = xc[htc * 256 + d];
        #pragma unroll 1
        for (int t = 0; t < 64; ++t) {
            float dltn = 0.f, un = 0.f;
            size_t htn = htc;
            if (t < 63) {
                int g = g0 + t + 1;
                int tt = dir ? 2047 - g : g;
                htn = (size_t)h * 2048 + tt;
                dltn = del[htn * 256 + d];
                un   = xc[htn * 256 + d];
            }
            float du = dlt * u;
            sS += dlt;
            #pragma unroll
            for (int j = 0; j < 64; ++j) {
                float a = __expf(A[j] * dlt);
                hreg[j] = a * hreg[j] + du * Bs[t][j];
            }
            htc = htn; dlt = dltn; u = un;
        }
    }
    size_t qb = (((size_t)hd * NC + c) * 128) * 256;
    #pragma unroll
    for (int j = 0; j < 64; ++j) Q[qb + (size_t)(n0 + j) * 256 + d] = hreg[j];
    if (nh == 0) S[((size_t)hd * NC + c) * 256 + d] = sS;
}

template<int NC>
__global__ void scan_pass2(const float* __restrict__ An, const float* __restrict__ S,
                           float* __restrict__ Q)
{
    int idx = blockIdx.x * 256 + threadIdx.x;   // 8*128*256 = 262144
    int hd = idx >> 15, rem = idx & 32767, n = rem >> 8, d = rem & 255;
    float A = An[(size_t)n * 256 + d];
    float hcur = 0.f;
    for (int c = 0; c < NC; ++c) {
        size_t o = (((size_t)hd * NC + c) * 128 + n) * 256 + d;
        float q = Q[o];
        Q[o] = hcur;                                    // chunk-start state
        hcur = __expf(A * S[((size_t)hd * NC + c) * 256 + d]) * hcur + q;
    }
}

template<int NC>
__global__ __launch_bounds__(256)
void scan_pass3(const float* __restrict__ del_f, const float* __restrict__ dbc_f,
                const float* __restrict__ xc_f, float* __restrict__ ys_f,
                const float* __restrict__ del_b, const float* __restrict__ dbc_b,
                const float* __restrict__ xc_b, float* __restrict__ ys_b,
                const float* __restrict__ An, const float* __restrict__ Q)
{
    constexpr int CH = 2048 / NC;
    __shared__ float BC[64][64][2];
    const int tid = threadIdx.x, lane = tid & 63, wv = tid >> 6;
    const int nh = blockIdx.x, c = blockIdx.y, hd = blockIdx.z;
    const int dir = hd >> 2, h = hd & 3;
    const int n0 = nh * 64, d = wv * 64 + lane;
    const float* del = dir ? del_b : del_f;
    const float* dbc = dir ? dbc_b : dbc_f;
    const float* xc  = dir ? xc_b  : xc_f;
    float* ys        = dir ? ys_b  : ys_f;

    float A[64], hreg[64];
    size_t qb = (((size_t)hd * NC + c) * 128) * 256;
    #pragma unroll
    for (int j = 0; j < 64; ++j) {
        A[j] = An[(size_t)(n0 + j) * 256 + d];
        hreg[j] = Q[qb + (size_t)(n0 + j) * 256 + d];
    }

    for (int seg = 0; seg < CH / 64; ++seg) {
        __syncthreads();
        for (int e = tid; e < 64 * 64; e += 256) {
            int t = e >> 6, j = e & 63;
            int g = c * CH + seg * 64 + t;
            int tt = dir ? 2047 - g : g;
            size_t ht = (size_t)h * 2048 + tt;
            float2 v = { dbc[ht * 264 + 8 + n0 + j], dbc[ht * 264 + 136 + n0 + j] };
            *reinterpret_cast<float2*>(&BC[t][j][0]) = v;
        }
        __syncthreads();

        int g0 = c * CH + seg * 64;
        int tt0 = dir ? 2047 - g0 : g0;
        size_t htc = (size_t)h * 2048 + tt0;
        float dlt = del[htc * 256 + d];
        float u   = xc[htc * 256 + d];
        #pragma unroll 1
        for (int t = 0; t < 64; ++t) {
            float dltn = 0.f, un = 0.f;
            size_t htn = htc;
            if (t < 63) {
                int g = g0 + t + 1;
                int tt = dir ? 2047 - g : g;
                htn = (size_t)h * 2048 + tt;
                dltn = del[htn * 256 + d];
                un   = xc[htn * 256 + d];
            }
            float du = dlt * u;
            float y = 0.f;
            #pragma unroll
            for (int j = 0; j < 64; ++j) {
                float2 bc = *reinterpret_cast<const float2*>(&BC[t][j][0]);
                float a = __expf(A[j] * dlt);
                hreg[j] = a * hreg[j] + du * bc.x;
                y += hreg[j] * bc.y;
            }
            atomicAdd(&ys[htc * 256 + d], y);
            htc = htn; dlt = dltn; u = un;
        }
    }
}

// An[n*256+d] = -exp(A_log[d*128+n])
__global__ void negexp_transpose(const float* __restrict__ A_log, float* __restrict__ An)
{
    int idx = blockIdx.x * 256 + threadIdx.x;   // 32768
    int n = idx >> 8, d = idx & 255;
    An[idx] = -__expf(A_log[d * 128 + n]);
}

__global__ void ycombine(const float* ysin, const float* __restrict__ xc,
                         const float* __restrict__ xz, const float* __restrict__ Dp,
                         float* yout)
{
    int idx = blockIdx.x * 256 + threadIdx.x;
    if (idx >= HT * 256) return;
    int c = idx & 255;
    size_t ht = idx >> 8;
    float z = xz[ht * 512 + 256 + c];
    float y = (ysin[idx] + xc[idx] * Dp[c]) * (z / (1.f + __expf(-z)));
    yout[idx] = y;
}

__global__ __launch_bounds__(256)
void rmsnorm_add(const float* __restrict__ xf, const float* __restrict__ xb,
                 const float* __restrict__ w, float* __restrict__ xn)
{
    int row  = blockIdx.x * 4 + (threadIdx.x >> 6);
    int lane = threadIdx.x & 63;
    size_t base = (size_t)row * 128;
    float a0 = xf[base + lane]      + xb[base + lane];
    float a1 = xf[base + 64 + lane] + xb[base + 64 + lane];
    float ss = a0 * a0 + a1 * a1;
    #pragma unroll
    for (int off = 32; off; off >>= 1) ss += __shfl_xor(ss, off);
    float r = rsqrtf(ss / 128.f + 1e-8f);
    xn[base + lane]      = a0 * r * w[lane];
    xn[base + 64 + lane] = a1 * r * w[64 + lane];
}

// ---------------------------------------------------------------------------
extern "C" void kernel_launch(void* const* d_in, const int* in_sizes, int n_in,
                              void* d_out, int out_size, void* d_ws, size_t ws_size,
                              hipStream_t stream)
{
    const float* x        = (const float*)d_in[0];
    const float* icw      = (const float*)d_in[1];
    const float* icb      = (const float*)d_in[2];
    const float* ocw      = (const float*)d_in[3];
    const float* ocb      = (const float*)d_in[4];
    const float* in_proj  = (const float*)d_in[5];
    const float* mconv_w  = (const float*)d_in[6];
    const float* mconv_b  = (const float*)d_in[7];
    const float* x_proj   = (const float*)d_in[8];
    const float* dt_w     = (const float*)d_in[9];
    const float* dt_b     = (const float*)d_in[10];
    const float* A_log    = (const float*)d_in[11];
    const float* Dp       = (const float*)d_in[12];
    const float* out_proj = (const float*)d_in[13];
    const float* norm_w   = (const float*)d_in[14];
    float* out = (float*)d_out;
    (void)in_sizes; (void)n_in; (void)out_size;

    float* w = (float*)d_ws;
    size_t off = 0;
    auto alloc = [&](size_t n) { float* p = w + off; off += n; return p; };
    float* p12   = alloc((size_t)4 * 1048576);  // conv1 partials; later W2l alias
    float* xp    = alloc(1048576);
    float* xz    = alloc((size_t)HT * 512);     // alias: Wt1h (before step 2)
    float* xc_f  = alloc((size_t)HT * 256);     // alias: Wt1l (pre-3), xn2t (post-7)
    float* xc_b  = alloc((size_t)HT * 256);
    float* dbc_f = alloc((size_t)HT * 264);
    float* dbc_b = alloc((size_t)HT * 264);
    float* del_f = alloc((size_t)HT * 256);
    float* del_b = alloc((size_t)HT * 256);
    float* ys_f  = alloc((size_t)HT * 256);     // ys_f+ys_b reused as conv2 partials
    float* ys_b  = alloc((size_t)HT * 256);
    float* xfo   = alloc((size_t)HT * 128);     // alias: xb1t (before step 8)
    float* xbo   = alloc((size_t)HT * 128);
    float* xn    = alloc((size_t)HT * 128);
    float* An    = alloc(32768);                // -exp(A_log) transposed [n][d]
    float* S     = alloc(65536);                // chunk delta sums [hd][NC][d]
    // Q gets the remainder: pick NCHUNK by what fits (runtime, deterministic).
    size_t remaining = ws_size / 4 - off;
    const int NC = (remaining >= (size_t)8 * 32 * 128 * 256) ? 32 : 16;
    float* Q = alloc((size_t)8 * NC * 128 * 256);

    // bf16 aliases (disjoint lifetimes)
    u16* Wt1h = (u16*)xz;     // dead before step 2
    u16* Wt1l = (u16*)xc_f;   // spans xc_f+xc_b; dead before step 3
    u16* xb1t = (u16*)xfo;    // dead before step 8
    u16* W2h  = (u16*)Q;      // written after scan (Q dead)
    u16* W2l  = (u16*)p12;    // written after conv1 combine (p12 dead)
    u16* xn2t = (u16*)xc_f;   // written after ycombine (xc dead)
    float* cp2 = ys_f;        // conv2 partials: 16 x 262144 = ys_f+ys_b

    // 0) transposed bf16 weights/inputs for conv1
    transpose_cast<true><<<dim3(4, 2048), 256, 0, stream>>>(icw, Wt1h, Wt1l, 512 * 128, 128);
    transpose_cast<false><<<dim3(64, 4), 256, 0, stream>>>(x, xb1t, nullptr, 128, 2048);

    // 1) input conv via MFMA (KSPLIT=4) + bias + silu
    conv_mfma<512, 128><<<dim3(4, 4, 16), 256, 0, stream>>>(xb1t, Wt1h, Wt1l, p12);
    conv_combine_silu<4><<<4096, 256, 0, stream>>>(p12, icb, xp, 512 * 2048);

    // 2) shared in_proj GEMM: xz = xp @ in_proj^T   (8192x512, K=128)
    gemm_nt<<<dim3(128, 8), 256, 0, stream>>>(xp, in_proj, xz, HT, 512, 128);

    // 3) depthwise conv + silu, both directions
    dwconv_silu<<<8192, 256, 0, stream>>>(xz, mconv_w, mconv_b, xc_f, 0);
    dwconv_silu<<<8192, 256, 0, stream>>>(xz, mconv_w, mconv_b, xc_b, 1);

    // 4) x_proj GEMMs: dbc = xc @ x_proj^T  (8192x264, K=256)
    gemm_nt<<<dim3(128, 5), 256, 0, stream>>>(xc_f, x_proj, dbc_f, HT, 264, 256);
    gemm_nt<<<dim3(128, 5), 256, 0, stream>>>(xc_b, x_proj, dbc_b, HT, 264, 256);

    // 5) delta = softplus(dt @ dt_w^T + dt_b)
    delta_softplus<<<8192, 256, 0, stream>>>(dbc_f, dt_w, dt_b, del_f);
    delta_softplus<<<8192, 256, 0, stream>>>(dbc_b, dt_w, dt_b, del_b);

    // 6) chunked selective scan (lane=d layout), fwd+bwd
    negexp_transpose<<<128, 256, 0, stream>>>(A_log, An);
    hipMemsetAsync(ys_f, 0, (size_t)HT * 256 * 4, stream);
    hipMemsetAsync(ys_b, 0, (size_t)HT * 256 * 4, stream);
    if (NC == 32) {
        scan_pass1<32><<<dim3(2, 32, 8), 256, 0, stream>>>(del_f, dbc_f, xc_f,
                                                           del_b, dbc_b, xc_b, An, Q, S);
        scan_pass2<32><<<1024, 256, 0, stream>>>(An, S, Q);
        scan_pass3<32><<<dim3(2, 32, 8), 256, 0, stream>>>(del_f, dbc_f, xc_f, ys_f,
                                                           del_b, dbc_b, xc_b, ys_b, An, Q);
    } else {
        scan_pass1<16><<<dim3(2, 16, 8), 256, 0, stream>>>(del_f, dbc_f, xc_f,
                                                           del_b, dbc_b, xc_b, An, Q, S);
        scan_pass2<16><<<1024, 256, 0, stream>>>(An, S, Q);
        scan_pass3<16><<<dim3(2, 16, 8), 256, 0, stream>>>(del_f, dbc_f, xc_f, ys_f,
                                                           del_b, dbc_b, xc_b, ys_b, An, Q);
    }

    // 7) y = (ys + xc*D) * silu(z)  (in place)
    ycombine<<<8192, 256, 0, stream>>>(ys_f, xc_f, xz, Dp, ys_f);
    ycombine<<<8192, 256, 0, stream>>>(ys_b, xc_b, xz, Dp, ys_b);

    // 8) out_proj GEMMs (8192x128, K=256)
    gemm_nt<<<dim3(128, 2), 256, 0, stream>>>(ys_f, out_proj, xfo, HT, 128, 256);
    gemm_nt<<<dim3(128, 2), 256, 0, stream>>>(ys_b, out_proj, xbo, HT, 128, 256);

    // 9) rmsnorm(xf + xb)
    rmsnorm_add<<<2048, 256, 0, stream>>>(xfo, xbo, norm_w, xn);

    // 9.5) transposed bf16 for conv2 (xn is [512][2048] flat-channel view)
    transpose_cast<false><<<dim3(64, 16), 256, 0, stream>>>(xn, xn2t, nullptr, 512, 2048);
    transpose_cast<true><<<dim3(4, 2048), 256, 0, stream>>>(ocw, W2h, W2l, 128 * 512, 128);

    // 10) output conv via MFMA (KSPLIT=16) + bias + silu -> d_out
    conv_mfma<128, 512><<<dim3(1, 16, 16), 256, 0, stream>>>(xn2t, W2h, W2l, cp2);
    conv_combine_silu<16><<<1024, 256, 0, stream>>>(cp2, ocb, out, 128 * 2048);
}

// Round 7
// 579.623 us; speedup vs baseline: 4.8364x; 1.1039x over previous
//
#include <hip/hip_runtime.h>
#include <math.h>
#include <cstddef>

// Problem constants (match reference)
#define SEQL   2048
#define DMODEL 128
#define NHEADS 4
#define DINNER 256
#define DSTATE 128
#define DTRANK 8
#define KWIDTH 128   // big conv kernel size
#define HT     (NHEADS*SEQL)   // 8192 rows for mamba GEMMs

typedef short bf16x8 __attribute__((ext_vector_type(8)));
typedef float f32x4  __attribute__((ext_vector_type(4)));
typedef unsigned short u16;

#if __has_builtin(__builtin_amdgcn_exp2f)
#define EXP2(x) __builtin_amdgcn_exp2f(x)
#else
#define EXP2(x) exp2f(x)
#endif
#define LOG2E 1.4426950408889634f

__device__ __forceinline__ u16 bf16rn(float f) {
    union { float f; unsigned u; } v; v.f = f;
    unsigned u = v.u + 0x7FFFu + ((v.u >> 16) & 1u);
    return (u16)(u >> 16);
}
__device__ __forceinline__ float bf16tof(u16 h) {
    union { unsigned u; float f; } v; v.u = ((unsigned)h) << 16;
    return v.f;
}

// ---------------------------------------------------------------------------
// Transpose + cast: in fp32 [R][C] -> out bf16 [C][R]. SPLIT: also write
// lo = bf16(x - float(hi)). R,C multiples of 32.
// ---------------------------------------------------------------------------
template<bool SPLIT>
__global__ __launch_bounds__(256)
void transpose_cast(const float* __restrict__ in, u16* __restrict__ outh,
                    u16* __restrict__ outl, int R, int C)
{
    __shared__ float T[32][33];
    const int r0 = blockIdx.y * 32, c0 = blockIdx.x * 32;
    {
        int ii = threadIdx.x >> 3, c4 = (threadIdx.x & 7) * 4;
        float4 v = *reinterpret_cast<const float4*>(in + (size_t)(r0 + ii) * C + c0 + c4);
        T[ii][c4 + 0] = v.x; T[ii][c4 + 1] = v.y; T[ii][c4 + 2] = v.z; T[ii][c4 + 3] = v.w;
    }
    __syncthreads();
    int cc = threadIdx.x >> 3, r4 = (threadIdx.x & 7) * 4;
    ushort4 h, l;
    float f0 = T[r4 + 0][cc], f1 = T[r4 + 1][cc], f2 = T[r4 + 2][cc], f3 = T[r4 + 3][cc];
    h.x = bf16rn(f0); h.y = bf16rn(f1); h.z = bf16rn(f2); h.w = bf16rn(f3);
    *reinterpret_cast<ushort4*>(outh + (size_t)(c0 + cc) * R + r0 + r4) = h;
    if (SPLIT) {
        l.x = bf16rn(f0 - bf16tof(h.x)); l.y = bf16rn(f1 - bf16tof(h.y));
        l.z = bf16rn(f2 - bf16tof(h.z)); l.w = bf16rn(f3 - bf16tof(h.w));
        *reinterpret_cast<ushort4*>(outl + (size_t)(c0 + cc) * R + r0 + r4) = l;
    }
}

// flat split-cast: fp32 [n] -> bf16 hi[n], lo[n]
__global__ __launch_bounds__(256)
void cast_split(const float* __restrict__ in, u16* __restrict__ h, u16* __restrict__ l, int n)
{
    int i4 = (blockIdx.x * 256 + threadIdx.x) * 4;
    if (i4 >= n) return;
    float4 v = *reinterpret_cast<const float4*>(in + i4);
    ushort4 hh, ll;
    hh.x = bf16rn(v.x); hh.y = bf16rn(v.y); hh.z = bf16rn(v.z); hh.w = bf16rn(v.w);
    ll.x = bf16rn(v.x - bf16tof(hh.x)); ll.y = bf16rn(v.y - bf16tof(hh.y));
    ll.z = bf16rn(v.z - bf16tof(hh.z)); ll.w = bf16rn(v.w - bf16tof(hh.w));
    *reinterpret_cast<ushort4*>(h + i4) = hh;
    *reinterpret_cast<ushort4*>(l + i4) = ll;
}

// ---------------------------------------------------------------------------
// Big conv as per-tap implicit GEMM on MFMA (see round-3 notes).
// ---------------------------------------------------------------------------
template<int O_TOTAL, int I_TOTAL>
__global__ __launch_bounds__(256)
void conv_mfma(const u16* __restrict__ Xg, const u16* __restrict__ Wh,
               const u16* __restrict__ Wlo, float* __restrict__ Yp)
{
    __shared__ u16 Xt[256][32];        // rows p = t0-63+r
    __shared__ u16 Ws[4][128][32];     // [kl*2+hl][o][i]
    const int tid = threadIdx.x;
    const int lane = tid & 63;
    const int wid = tid >> 6;
    const int wo = wid >> 1, wt = wid & 1;
    const int o0 = blockIdx.x * 128;
    const int i0 = blockIdx.y * 32;
    const int t0 = blockIdx.z * 128;
    const int l15 = lane & 15, l4 = lane >> 4;

    #pragma unroll
    for (int it = 0; it < 4; ++it) {
        int e = it * 2048 + tid * 8;
        int r = e >> 5, col = e & 31;
        int p = t0 - 63 + r;
        bf16x8 v = {};
        if (p >= 0 && p < 2048)
            v = *reinterpret_cast<const bf16x8*>(Xg + (size_t)p * I_TOTAL + i0 + col);
        *reinterpret_cast<bf16x8*>(&Xt[r][col]) = v;
    }

    f32x4 acc[4][4];
    #pragma unroll
    for (int a = 0; a < 4; ++a)
        #pragma unroll
        for (int b = 0; b < 4; ++b) acc[a][b] = (f32x4){0.f, 0.f, 0.f, 0.f};

    const size_t wstride = (size_t)O_TOTAL * I_TOTAL;
    bf16x8 wreg[8];
    #pragma unroll
    for (int it = 0; it < 8; ++it) {
        int e = it * 2048 + tid * 8;
        int s = e >> 12; int kloc = s >> 1, hl = s & 1;
        const u16* src = hl ? Wlo : Wh;
        wreg[it] = *reinterpret_cast<const bf16x8*>(
            src + (size_t)kloc * wstride + (size_t)(o0 + ((e >> 5) & 127)) * I_TOTAL + i0 + (e & 31));
    }

    for (int tp = 0; tp < 64; ++tp) {
        __syncthreads();
        #pragma unroll
        for (int it = 0; it < 8; ++it) {
            int e = it * 2048 + tid * 8;
            *reinterpret_cast<bf16x8*>(&Ws[e >> 12][(e >> 5) & 127][e & 31]) = wreg[it];
        }
        if (tp + 1 < 64) {
            int k0n = (tp + 1) * 2;
            #pragma unroll
            for (int it = 0; it < 8; ++it) {
                int e = it * 2048 + tid * 8;
                int s = e >> 12; int kloc = s >> 1, hl = s & 1;
                const u16* src = hl ? Wlo : Wh;
                wreg[it] = *reinterpret_cast<const bf16x8*>(
                    src + (size_t)(k0n + kloc) * wstride + (size_t)(o0 + ((e >> 5) & 127)) * I_TOTAL + i0 + (e & 31));
            }
        }
        __syncthreads();
        #pragma unroll
        for (int kl = 0; kl < 2; ++kl) {
            const int k = tp * 2 + kl;
            bf16x8 B[4];
            #pragma unroll
            for (int b = 0; b < 4; ++b) {
                int row = wt * 64 + b * 16 + l15 + k;
                B[b] = *reinterpret_cast<const bf16x8*>(&Xt[row][l4 * 8]);
            }
            #pragma unroll
            for (int hl = 0; hl < 2; ++hl) {
                #pragma unroll
                for (int a = 0; a < 4; ++a) {
                    bf16x8 A = *reinterpret_cast<const bf16x8*>(
                        &Ws[kl * 2 + hl][wo * 64 + a * 16 + l15][l4 * 8]);
                    #pragma unroll
                    for (int b = 0; b < 4; ++b)
                        acc[a][b] = __builtin_amdgcn_mfma_f32_16x16x32_bf16(A, B[b], acc[a][b], 0, 0, 0);
                }
            }
        }
    }

    float* outp = Yp + (size_t)blockIdx.y * ((size_t)O_TOTAL * 2048);
    #pragma unroll
    for (int a = 0; a < 4; ++a)
        #pragma unroll
        for (int b = 0; b < 4; ++b) {
            int col = t0 + wt * 64 + b * 16 + l15;
            #pragma unroll
            for (int r = 0; r < 4; ++r) {
                int row = o0 + wo * 64 + a * 16 + l4 * 4 + r;
                outp[(size_t)row * 2048 + col] = acc[a][b][r];
            }
        }
}

template<int KSPLIT>
__global__ void conv_combine_silu(const float* __restrict__ Yp, const float* __restrict__ bias,
                                  float* __restrict__ out, int total)
{
    int f = blockIdx.x * 256 + threadIdx.x;
    if (f >= total) return;
    float s = bias[f >> 11];
    #pragma unroll
    for (int z = 0; z < KSPLIT; ++z) s += Yp[(size_t)z * total + f];
    out[f] = s / (1.f + __expf(-s));
}

// ---------------------------------------------------------------------------
// Split-bf16 MFMA GEMM: C[M][N] = A[M][K]*B[N][K]^T via Ah*Bh + Ah*Bl + Al*Bh.
// Tile 128Mx64N, BK=64, 256 thr = 4 waves (2Mx2N), wave 64Mx32N (4x2 frags).
// LDS rows padded to 72 u16 (144B) to avoid 128B-stride bank conflicts.
// ---------------------------------------------------------------------------
__global__ __launch_bounds__(256)
void gemm_mfma_split(const u16* __restrict__ Ah, const u16* __restrict__ Al,
                     const u16* __restrict__ Bh, const u16* __restrict__ Bl,
                     float* __restrict__ C, int M, int N, int K)
{
    __shared__ u16 As[2][128][72];
    __shared__ u16 Bs[2][64][72];
    const int tid = threadIdx.x, lane = tid & 63, wid = tid >> 6;
    const int wm = wid >> 1, wn = wid & 1;
    const int m0 = blockIdx.x * 128, n0 = blockIdx.y * 64;
    const int l15 = lane & 15, l4 = lane >> 4;

    f32x4 acc[4][2];
    #pragma unroll
    for (int a = 0; a < 4; ++a)
        #pragma unroll
        for (int b = 0; b < 2; ++b) acc[a][b] = (f32x4){0.f, 0.f, 0.f, 0.f};

    for (int k0 = 0; k0 < K; k0 += 64) {
        __syncthreads();
        #pragma unroll
        for (int it = 0; it < 4; ++it) {
            int e = it * 2048 + tid * 8;
            int r = e >> 6, cc = e & 63;
            *reinterpret_cast<bf16x8*>(&As[0][r][cc]) =
                *reinterpret_cast<const bf16x8*>(Ah + (size_t)(m0 + r) * K + k0 + cc);
            *reinterpret_cast<bf16x8*>(&As[1][r][cc]) =
                *reinterpret_cast<const bf16x8*>(Al + (size_t)(m0 + r) * K + k0 + cc);
        }
        #pragma unroll
        for (int it = 0; it < 2; ++it) {
            int e = it * 2048 + tid * 8;
            int r = e >> 6, cc = e & 63;
            bf16x8 vh = {}, vl = {};
            if (n0 + r < N) {
                vh = *reinterpret_cast<const bf16x8*>(Bh + (size_t)(n0 + r) * K + k0 + cc);
                vl = *reinterpret_cast<const bf16x8*>(Bl + (size_t)(n0 + r) * K + k0 + cc);
            }
            *reinterpret_cast<bf16x8*>(&Bs[0][r][cc]) = vh;
            *reinterpret_cast<bf16x8*>(&Bs[1][r][cc]) = vl;
        }
        __syncthreads();
        #pragma unroll
        for (int ks = 0; ks < 2; ++ks) {
            bf16x8 afh[4], afl[4], bfh[2], bfl[2];
            #pragma unroll
            for (int b = 0; b < 2; ++b) {
                bfh[b] = *reinterpret_cast<const bf16x8*>(&Bs[0][wn*32 + b*16 + l15][ks*32 + l4*8]);
                bfl[b] = *reinterpret_cast<const bf16x8*>(&Bs[1][wn*32 + b*16 + l15][ks*32 + l4*8]);
            }
            #pragma unroll
            for (int a = 0; a < 4; ++a) {
                afh[a] = *reinterpret_cast<const bf16x8*>(&As[0][wm*64 + a*16 + l15][ks*32 + l4*8]);
                afl[a] = *reinterpret_cast<const bf16x8*>(&As[1][wm*64 + a*16 + l15][ks*32 + l4*8]);
            }
            #pragma unroll
            for (int a = 0; a < 4; ++a)
                #pragma unroll
                for (int b = 0; b < 2; ++b) {
                    acc[a][b] = __builtin_amdgcn_mfma_f32_16x16x32_bf16(afh[a], bfh[b], acc[a][b], 0, 0, 0);
                    acc[a][b] = __builtin_amdgcn_mfma_f32_16x16x32_bf16(afh[a], bfl[b], acc[a][b], 0, 0, 0);
                    acc[a][b] = __builtin_amdgcn_mfma_f32_16x16x32_bf16(afl[a], bfh[b], acc[a][b], 0, 0, 0);
                }
        }
    }
    #pragma unroll
    for (int a = 0; a < 4; ++a)
        #pragma unroll
        for (int b = 0; b < 2; ++b) {
            int col = n0 + wn * 32 + b * 16 + l15;
            if (col < N) {
                #pragma unroll
                for (int r = 0; r < 4; ++r) {
                    int row = m0 + wm * 64 + a * 16 + l4 * 4 + r;
                    C[(size_t)row * N + col] = acc[a][b][r];
                }
            }
        }
}

// ---------------------------------------------------------------------------
// depthwise conv (7 taps) + silu
// ---------------------------------------------------------------------------
__global__ void dwconv_silu(const float* __restrict__ xz, const float* __restrict__ w7,
                            const float* __restrict__ cb, float* __restrict__ xc, int dir)
{
    int idx = blockIdx.x * 256 + threadIdx.x;
    if (idx >= HT * 256) return;
    int c = idx & 255;
    int ht = idx >> 8;
    int h = ht >> 11, t = ht & 2047;
    float s = cb[c];
    #pragma unroll
    for (int k = 0; k < 7; ++k) {
        int tt = dir ? (t + 6 - k) : (t - 6 + k);
        if (tt >= 0 && tt < SEQL)
            s += w7[c * 7 + k] * xz[((size_t)(h << 11) + tt) * 512 + c];
    }
    xc[idx] = s / (1.f + __expf(-s));
}

__global__ void delta_softplus(const float* __restrict__ dbc, const float* __restrict__ dtw,
                               const float* __restrict__ dtb, float* __restrict__ delta)
{
    int idx = blockIdx.x * 256 + threadIdx.x;
    if (idx >= HT * 256) return;
    int c = idx & 255;
    int ht = idx >> 8;
    const float* dr = dbc + (size_t)ht * 264;
    float s = dtb[c];
    #pragma unroll
    for (int r = 0; r < 8; ++r) s += dr[r] * dtw[c * 8 + r];
    delta[idx] = (s > 20.f) ? s : log1pf(__expf(s));
}

// ---------------------------------------------------------------------------
// Chunked selective scan, lane=d layout (see round-5 notes).
// A2[n*256+d] = -exp(A_log[d*128+n]) * log2(e); decays via hardware exp2.
// pass1: local chunk scan -> Q (end state) + S (sum delta). B pair-packed b64.
// pass2: chunk combine, Q <- chunk-start state.
// pass3: rescan + y accumulate; {B,C} pair-packed b128 broadcasts.
// ---------------------------------------------------------------------------
template<int NC>
__global__ __launch_bounds__(256)
void scan_pass1(const float* __restrict__ del_f, const float* __restrict__ dbc_f,
                const float* __restrict__ xc_f,
                const float* __restrict__ del_b, const float* __restrict__ dbc_b,
                const float* __restrict__ xc_b,
                const float* __restrict__ A2, float* __restrict__ Q, float* __restrict__ S)
{
    constexpr int CH = 2048 / NC;
    __shared__ float2 Bs2[64][32];
    const int tid = threadIdx.x, lane = tid & 63, wv = tid >> 6;
    const int nh = blockIdx.x, c = blockIdx.y, hd = blockIdx.z;
    const int dir = hd >> 2, h = hd & 3;
    const int n0 = nh * 64, d = wv * 64 + lane;
    const float* del = dir ? del_b : del_f;
    const float* dbc = dir ? dbc_b : dbc_f;
    const float* xc  = dir ? xc_b  : xc_f;

    float A[64], hreg[64];
    #pragma unroll
    for (int j = 0; j < 64; ++j) { A[j] = A2[(size_t)(n0 + j) * 256 + d]; hreg[j] = 0.f; }
    float sS = 0.f;

    for (int seg = 0; seg < CH / 64; ++seg) {
        __syncthreads();
        for (int e = tid; e < 64 * 32; e += 256) {
            int t = e >> 5, j2 = e & 31;
            int g = c * CH + seg * 64 + t;
            int tt = dir ? 2047 - g : g;
            Bs2[t][j2] = *reinterpret_cast<const float2*>(
                &dbc[((size_t)h * 2048 + tt) * 264 + 8 + n0 + 2 * j2]);
        }
        __syncthreads();

        int g0 = c * CH + seg * 64;
        int tt0 = dir ? 2047 - g0 : g0;
        size_t htc = (size_t)h * 2048 + tt0;
        float dlt = del[htc * 256 + d];
        float u   = xc[htc * 256 + d];
        #pragma unroll 1
        for (int t = 0; t < 64; ++t) {
            float dltn = 0.f, un = 0.f;
            size_t htn = htc;
            if (t < 63) {
                int g = g0 + t + 1;
                int tt = dir ? 2047 - g : g;
                htn = (size_t)h * 2048 + tt;
                dltn = del[htn * 256 + d];
                un   = xc[htn * 256 + d];
            }
            float du = dlt * u;
            sS += dlt;
            #pragma unroll
            for (int j2 = 0; j2 < 32; ++j2) {
                float2 bb = Bs2[t][j2];
                hreg[2*j2]   = EXP2(A[2*j2]   * dlt) * hreg[2*j2]   + du * bb.x;
                hreg[2*j2+1] = EXP2(A[2*j2+1] * dlt) * hreg[2*j2+1] + du * bb.y;
            }
            htc = htn; dlt = dltn; u = un;
        }
    }
    size_t qb = (((size_t)hd * NC + c) * 128) * 256;
    #pragma unroll
    for (int j = 0; j < 64; ++j) Q[qb + (size_t)(n0 + j) * 256 + d] = hreg[j];
    if (nh == 0) S[((size_t)hd * NC + c) * 256 + d] = sS;
}

template<int NC>
__global__ void scan_pass2(const float* __restrict__ A2, const float* __restrict__ S,
                           float* __restrict__ Q)
{
    int idx = blockIdx.x * 256 + threadIdx.x;   // 8*128*256 = 262144
    int hd = idx >> 15, rem = idx & 32767, n = rem >> 8, d = rem & 255;
    float A = A2[(size_t)n * 256 + d];
    float hcur = 0.f;
    for (int c = 0; c < NC; ++c) {
        size_t o = (((size_t)hd * NC + c) * 128 + n) * 256 + d;
        float q = Q[o];
        Q[o] = hcur;                                    // chunk-start state
        hcur = EXP2(A * S[((size_t)hd * NC + c) * 256 + d]) * hcur + q;
    }
}

template<int NC>
__global__ __launch_bounds__(256)
void scan_pass3(const float* __restrict__ del_f, const float* __restrict__ dbc_f,
                const float* __restrict__ xc_f, float* __restrict__ ys_f,
                const float* __restrict__ del_b, const float* __restrict__ dbc_b,
                const float* __restrict__ xc_b, float* __restrict__ ys_b,
                const float* __restrict__ A2, const float* __restrict__ Q)
{
    constexpr int CH = 2048 / NC;
    __shared__ float4 BC4[64][32];
    const int tid = threadIdx.x, lane = tid & 63, wv = tid >> 6;
    const int nh = blockIdx.x, c = blockIdx.y, hd = blockIdx.z;
    const int dir = hd >> 2, h = hd & 3;
    const int n0 = nh * 64, d = wv * 64 + lane;
    const float* del = dir ? del_b : del_f;
    const float* dbc = dir ? dbc_b : dbc_f;
    const float* xc  = dir ? xc_b  : xc_f;
    float* ys        = dir ? ys_b  : ys_f;

    float A[64], hreg[64];
    size_t qb = (((size_t)hd * NC + c) * 128) * 256;
    #pragma unroll
    for (int j = 0; j < 64; ++j) {
        A[j] = A2[(size_t)(n0 + j) * 256 + d];
        hreg[j] = Q[qb + (size_t)(n0 + j) * 256 + d];
    }

    for (int seg = 0; seg < CH / 64; ++seg) {
        __syncthreads();
        for (int e = tid; e < 64 * 32; e += 256) {
            int t = e >> 5, j2 = e & 31;
            int g = c * CH + seg * 64 + t;
            int tt = dir ? 2047 - g : g;
            size_t ht = (size_t)h * 2048 + tt;
            float2 b2 = *reinterpret_cast<const float2*>(&dbc[ht * 264 + 8   + n0 + 2 * j2]);
            float2 c2 = *reinterpret_cast<const float2*>(&dbc[ht * 264 + 136 + n0 + 2 * j2]);
            BC4[t][j2] = (float4){b2.x, c2.x, b2.y, c2.y};
        }
        __syncthreads();

        int g0 = c * CH + seg * 64;
        int tt0 = dir ? 2047 - g0 : g0;
        size_t htc = (size_t)h * 2048 + tt0;
        float dlt = del[htc * 256 + d];
        float u   = xc[htc * 256 + d];
        #pragma unroll 1
        for (int t = 0; t < 64; ++t) {
            float dltn = 0.f, un = 0.f;
            size_t htn = htc;
            if (t < 63) {
                int g = g0 + t + 1;
                int tt = dir ? 2047 - g : g;
                htn = (size_t)h * 2048 + tt;
                dltn = del[htn * 256 + d];
                un   = xc[htn * 256 + d];
            }
            float du = dlt * u;
            float y = 0.f;
            #pragma unroll
            for (int j2 = 0; j2 < 32; ++j2) {
                float4 bc = BC4[t][j2];
                hreg[2*j2]   = EXP2(A[2*j2]   * dlt) * hreg[2*j2]   + du * bc.x;
                y += hreg[2*j2] * bc.y;
                hreg[2*j2+1] = EXP2(A[2*j2+1] * dlt) * hreg[2*j2+1] + du * bc.z;
                y += hreg[2*j2+1] * bc.w;
            }
            atomicAdd(&ys[htc * 256 + d], y);
            htc = htn; dlt = dltn; u = un;
        }
    }
}

// A2[n*256+d] = -exp(A_log[d*128+n]) * log2(e)
__global__ void negexp_transpose(const float* __restrict__ A_log, float* __restrict__ A2)
{
    int idx = blockIdx.x * 256 + threadIdx.x;   // 32768
    int n = idx >> 8, d = idx & 255;
    A2[idx] = -__expf(A_log[d * 128 + n]) * LOG2E;
}

__global__ void ycombine(const float* ysin, const float* __restrict__ xc,
                         const float* __restrict__ xz, const float* __restrict__ Dp,
                         float* yout)
{
    int idx = blockIdx.x * 256 + threadIdx.x;
    if (idx >= HT * 256) return;
    int c = idx & 255;
    size_t ht = idx >> 8;
    float z = xz[ht * 512 + 256 + c];
    float y = (ysin[idx] + xc[idx] * Dp[c]) * (z / (1.f + __expf(-z)));
    yout[idx] = y;
}

__global__ __launch_bounds__(256)
void rmsnorm_add(const float* __restrict__ xf, const float* __restrict__ xb,
                 const float* __restrict__ w, float* __restrict__ xn)
{
    int row  = blockIdx.x * 4 + (threadIdx.x >> 6);
    int lane = threadIdx.x & 63;
    size_t base = (size_t)row * 128;
    float a0 = xf[base + lane]      + xb[base + lane];
    float a1 = xf[base + 64 + lane] + xb[base + 64 + lane];
    float ss = a0 * a0 + a1 * a1;
    #pragma unroll
    for (int off = 32; off; off >>= 1) ss += __shfl_xor(ss, off);
    float r = rsqrtf(ss / 128.f + 1e-8f);
    xn[base + lane]      = a0 * r * w[lane];
    xn[base + 64 + lane] = a1 * r * w[64 + lane];
}

// ---------------------------------------------------------------------------
extern "C" void kernel_launch(void* const* d_in, const int* in_sizes, int n_in,
                              void* d_out, int out_size, void* d_ws, size_t ws_size,
                              hipStream_t stream)
{
    const float* x        = (const float*)d_in[0];
    const float* icw      = (const float*)d_in[1];
    const float* icb      = (const float*)d_in[2];
    const float* ocw      = (const float*)d_in[3];
    const float* ocb      = (const float*)d_in[4];
    const float* in_proj  = (const float*)d_in[5];
    const float* mconv_w  = (const float*)d_in[6];
    const float* mconv_b  = (const float*)d_in[7];
    const float* x_proj   = (const float*)d_in[8];
    const float* dt_w     = (const float*)d_in[9];
    const float* dt_b     = (const float*)d_in[10];
    const float* A_log    = (const float*)d_in[11];
    const float* Dp       = (const float*)d_in[12];
    const float* out_proj = (const float*)d_in[13];
    const float* norm_w   = (const float*)d_in[14];
    float* out = (float*)d_out;
    (void)in_sizes; (void)n_in; (void)out_size;

    float* w = (float*)d_ws;
    size_t off = 0;
    auto alloc = [&](size_t n) { float* p = w + off; off += n; return p; };
    float* p12   = alloc((size_t)4 * 1048576);  // conv1 partials; xp/xc splits; W2l
    float* xp    = alloc(1048576);
    float* xz    = alloc((size_t)HT * 512);     // alias: Wt1h (before step 2)
    float* xc_f  = alloc((size_t)HT * 256);     // alias: Wt1l (pre-3), xn2t (post-7)
    float* xc_b  = alloc((size_t)HT * 256);
    float* dbc_f = alloc((size_t)HT * 264);
    float* dbc_b = alloc((size_t)HT * 264);
    float* del_f = alloc((size_t)HT * 256);
    float* del_b = alloc((size_t)HT * 256);
    float* ys_f  = alloc((size_t)HT * 256);     // ys_f+ys_b reused as conv2 partials
    float* ys_b  = alloc((size_t)HT * 256);
    float* xfo   = alloc((size_t)HT * 128);     // alias: xb1t (before step 8)
    float* xbo   = alloc((size_t)HT * 128);
    float* xn    = alloc((size_t)HT * 128);
    float* A2    = alloc(32768);                // -exp(A_log)*log2e, [n][d]
    float* S     = alloc(65536);                // chunk delta sums [hd][NC][d]
    float* Wsp   = alloc(262144);               // split projection weights (u16 packed)
    size_t remaining = ws_size / 4 - off;
    const int NC = (remaining >= (size_t)8 * 32 * 128 * 256) ? 32 : 16;
    float* Q = alloc((size_t)8 * NC * 128 * 256);

    // bf16 aliases (disjoint lifetimes)
    u16* Wt1h = (u16*)xz;     // dead before step 2
    u16* Wt1l = (u16*)xc_f;   // spans xc_f+xc_b; dead before step 3
    u16* xb1t = (u16*)xfo;    // dead before step 8
    u16* W2h  = (u16*)Q;      // written at 9.5 (Q + ys-splits dead)
    u16* W2l  = (u16*)p12;    // written at 9.5 (xc splits dead)
    u16* xn2t = (u16*)xc_f;   // written after ycombine (xc dead)
    float* cp2 = ys_f;        // conv2 partials: 16 x 262144 = ys_f+ys_b

    // split projection weights (in Wsp, u16 offsets)
    u16* W16 = (u16*)Wsp;
    u16* ip_h  = W16;           u16* ip_l  = W16 + 65536;
    u16* xpj_h = W16 + 131072;  u16* xpj_l = W16 + 198656;
    u16* opj_h = W16 + 266240;  u16* opj_l = W16 + 299008;
    // split activations (aliased)
    u16* xp_h  = (u16*)p12;                 u16* xp_l  = (u16*)(p12 + 524288);
    u16* xcf_h = (u16*)p12;                 u16* xcf_l = (u16*)(p12 + 1048576);
    u16* xcb_h = (u16*)(p12 + 2097152);     u16* xcb_l = (u16*)(p12 + 3145728);
    u16* ysf_h = (u16*)Q;                   u16* ysf_l = (u16*)(Q + 1048576);
    u16* ysb_h = (u16*)(Q + 2097152);       u16* ysb_l = (u16*)(Q + 3145728);

    // 0) transposed bf16 weights/inputs for conv1; scan A2; proj weight splits
    transpose_cast<true><<<dim3(4, 2048), 256, 0, stream>>>(icw, Wt1h, Wt1l, 512 * 128, 128);
    transpose_cast<false><<<dim3(64, 4), 256, 0, stream>>>(x, xb1t, nullptr, 128, 2048);
    negexp_transpose<<<128, 256, 0, stream>>>(A_log, A2);
    cast_split<<<64, 256, 0, stream>>>(in_proj, ip_h, ip_l, 65536);
    cast_split<<<66, 256, 0, stream>>>(x_proj, xpj_h, xpj_l, 67584);
    cast_split<<<32, 256, 0, stream>>>(out_proj, opj_h, opj_l, 32768);

    // 1) input conv via MFMA (KSPLIT=4) + bias + silu
    conv_mfma<512, 128><<<dim3(4, 4, 16), 256, 0, stream>>>(xb1t, Wt1h, Wt1l, p12);
    conv_combine_silu<4><<<4096, 256, 0, stream>>>(p12, icb, xp, 512 * 2048);

    // 2) in_proj GEMM: xz = xp @ in_proj^T  (8192x512, K=128), split MFMA
    cast_split<<<1024, 256, 0, stream>>>(xp, xp_h, xp_l, 1048576);
    gemm_mfma_split<<<dim3(64, 8), 256, 0, stream>>>(xp_h, xp_l, ip_h, ip_l, xz, HT, 512, 128);

    // 3) depthwise conv + silu, both directions
    dwconv_silu<<<8192, 256, 0, stream>>>(xz, mconv_w, mconv_b, xc_f, 0);
    dwconv_silu<<<8192, 256, 0, stream>>>(xz, mconv_w, mconv_b, xc_b, 1);

    // 4) x_proj GEMMs: dbc = xc @ x_proj^T  (8192x264, K=256), split MFMA
    cast_split<<<2048, 256, 0, stream>>>(xc_f, xcf_h, xcf_l, 2097152);
    cast_split<<<2048, 256, 0, stream>>>(xc_b, xcb_h, xcb_l, 2097152);
    gemm_mfma_split<<<dim3(64, 5), 256, 0, stream>>>(xcf_h, xcf_l, xpj_h, xpj_l, dbc_f, HT, 264, 256);
    gemm_mfma_split<<<dim3(64, 5), 256, 0, stream>>>(xcb_h, xcb_l, xpj_h, xpj_l, dbc_b, HT, 264, 256);

    // 5) delta = softplus(dt @ dt_w^T + dt_b)
    delta_softplus<<<8192, 256, 0, stream>>>(dbc_f, dt_w, dt_b, del_f);
    delta_softplus<<<8192, 256, 0, stream>>>(dbc_b, dt_w, dt_b, del_b);

    // 6) chunked selective scan (lane=d layout), fwd+bwd
    hipMemsetAsync(ys_f, 0, (size_t)HT * 256 * 4, stream);
    hipMemsetAsync(ys_b, 0, (size_t)HT * 256 * 4, stream);
    if (NC == 32) {
        scan_pass1<32><<<dim3(2, 32, 8), 256, 0, stream>>>(del_f, dbc_f, xc_f,
                                                           del_b, dbc_b, xc_b, A2, Q, S);
        scan_pass2<32><<<1024, 256, 0, stream>>>(A2, S, Q);
        scan_pass3<32><<<dim3(2, 32, 8), 256, 0, stream>>>(del_f, dbc_f, xc_f, ys_f,
                                                           del_b, dbc_b, xc_b, ys_b, A2, Q);
    } else {
        scan_pass1<16><<<dim3(2, 16, 8), 256, 0, stream>>>(del_f, dbc_f, xc_f,
                                                           del_b, dbc_b, xc_b, A2, Q, S);
        scan_pass2<16><<<1024, 256, 0, stream>>>(A2, S, Q);
        scan_pass3<16><<<dim3(2, 16, 8), 256, 0, stream>>>(del_f, dbc_f, xc_f, ys_f,
                                                           del_b, dbc_b, xc_b, ys_b, A2, Q);
    }

    // 7) y = (ys + xc*D) * silu(z)  (in place)
    ycombine<<<8192, 256, 0, stream>>>(ys_f, xc_f, xz, Dp, ys_f);
    ycombine<<<8192, 256, 0, stream>>>(ys_b, xc_b, xz, Dp, ys_b);

    // 8) out_proj GEMMs (8192x128, K=256), split MFMA
    cast_split<<<2048, 256, 0, stream>>>(ys_f, ysf_h, ysf_l, 2097152);
    cast_split<<<2048, 256, 0, stream>>>(ys_b, ysb_h, ysb_l, 2097152);
    gemm_mfma_split<<<dim3(64, 2), 256, 0, stream>>>(ysf_h, ysf_l, opj_h, opj_l, xfo, HT, 128, 256);
    gemm_mfma_split<<<dim3(64, 2), 256, 0, stream>>>(ysb_h, ysb_l, opj_h, opj_l, xbo, HT, 128, 256);

    // 9) rmsnorm(xf + xb)
    rmsnorm_add<<<2048, 256, 0, stream>>>(xfo, xbo, norm_w, xn);

    // 9.5) transposed bf16 for conv2 (xn is [512][2048] flat-channel view)
    transpose_cast<false><<<dim3(64, 16), 256, 0, stream>>>(xn, xn2t, nullptr, 512, 2048);
    transpose_cast<true><<<dim3(4, 2048), 256, 0, stream>>>(ocw, W2h, W2l, 128 * 512, 128);

    // 10) output conv via MFMA (KSPLIT=16) + bias + silu -> d_out
    conv_mfma<128, 512><<<dim3(1, 16, 16), 256, 0, stream>>>(xn2t, W2h, W2l, cp2);
    conv_combine_silu<16><<<1024, 256, 0, stream>>>(cp2, ocb, out, 128 * 2048);
}

// Round 8
// 555.645 us; speedup vs baseline: 5.0451x; 1.0432x over previous
//
#include <hip/hip_runtime.h>
#include <math.h>
#include <cstddef>

// Problem constants (match reference)
#define SEQL   2048
#define DMODEL 128
#define NHEADS 4
#define DINNER 256
#define DSTATE 128
#define DTRANK 8
#define KWIDTH 128   // big conv kernel size
#define HT     (NHEADS*SEQL)   // 8192 rows for mamba GEMMs

typedef short bf16x8 __attribute__((ext_vector_type(8)));
typedef float f32x4  __attribute__((ext_vector_type(4)));
typedef unsigned short u16;

#if __has_builtin(__builtin_amdgcn_exp2f)
#define EXP2(x) __builtin_amdgcn_exp2f(x)
#else
#define EXP2(x) exp2f(x)
#endif
#define LOG2E 1.4426950408889634f

__device__ __forceinline__ u16 bf16rn(float f) {
    union { float f; unsigned u; } v; v.f = f;
    unsigned u = v.u + 0x7FFFu + ((v.u >> 16) & 1u);
    return (u16)(u >> 16);
}
__device__ __forceinline__ float bf16tof(u16 h) {
    union { unsigned u; float f; } v; v.u = ((unsigned)h) << 16;
    return v.f;
}

// ---------------------------------------------------------------------------
// Transpose + cast: in fp32 [R][C] -> out bf16 [C][R]. SPLIT: also write
// lo = bf16(x - float(hi)). R,C multiples of 32.
// ---------------------------------------------------------------------------
template<bool SPLIT>
__global__ __launch_bounds__(256)
void transpose_cast(const float* __restrict__ in, u16* __restrict__ outh,
                    u16* __restrict__ outl, int R, int C)
{
    __shared__ float T[32][33];
    const int r0 = blockIdx.y * 32, c0 = blockIdx.x * 32;
    {
        int ii = threadIdx.x >> 3, c4 = (threadIdx.x & 7) * 4;
        float4 v = *reinterpret_cast<const float4*>(in + (size_t)(r0 + ii) * C + c0 + c4);
        T[ii][c4 + 0] = v.x; T[ii][c4 + 1] = v.y; T[ii][c4 + 2] = v.z; T[ii][c4 + 3] = v.w;
    }
    __syncthreads();
    int cc = threadIdx.x >> 3, r4 = (threadIdx.x & 7) * 4;
    ushort4 h, l;
    float f0 = T[r4 + 0][cc], f1 = T[r4 + 1][cc], f2 = T[r4 + 2][cc], f3 = T[r4 + 3][cc];
    h.x = bf16rn(f0); h.y = bf16rn(f1); h.z = bf16rn(f2); h.w = bf16rn(f3);
    *reinterpret_cast<ushort4*>(outh + (size_t)(c0 + cc) * R + r0 + r4) = h;
    if (SPLIT) {
        l.x = bf16rn(f0 - bf16tof(h.x)); l.y = bf16rn(f1 - bf16tof(h.y));
        l.z = bf16rn(f2 - bf16tof(h.z)); l.w = bf16rn(f3 - bf16tof(h.w));
        *reinterpret_cast<ushort4*>(outl + (size_t)(c0 + cc) * R + r0 + r4) = l;
    }
}

// flat split-cast: fp32 [n] -> bf16 hi[n], lo[n]  (weights only now)
__global__ __launch_bounds__(256)
void cast_split(const float* __restrict__ in, u16* __restrict__ h, u16* __restrict__ l, int n)
{
    int i4 = (blockIdx.x * 256 + threadIdx.x) * 4;
    if (i4 >= n) return;
    float4 v = *reinterpret_cast<const float4*>(in + i4);
    ushort4 hh, ll;
    hh.x = bf16rn(v.x); hh.y = bf16rn(v.y); hh.z = bf16rn(v.z); hh.w = bf16rn(v.w);
    ll.x = bf16rn(v.x - bf16tof(hh.x)); ll.y = bf16rn(v.y - bf16tof(hh.y));
    ll.z = bf16rn(v.z - bf16tof(hh.z)); ll.w = bf16rn(v.w - bf16tof(hh.w));
    *reinterpret_cast<ushort4*>(h + i4) = hh;
    *reinterpret_cast<ushort4*>(l + i4) = ll;
}

// ---------------------------------------------------------------------------
// Big conv as per-tap implicit GEMM on MFMA (see round-3 notes).
// ---------------------------------------------------------------------------
template<int O_TOTAL, int I_TOTAL>
__global__ __launch_bounds__(256)
void conv_mfma(const u16* __restrict__ Xg, const u16* __restrict__ Wh,
               const u16* __restrict__ Wlo, float* __restrict__ Yp)
{
    __shared__ u16 Xt[256][32];        // rows p = t0-63+r
    __shared__ u16 Ws[4][128][32];     // [kl*2+hl][o][i]
    const int tid = threadIdx.x;
    const int lane = tid & 63;
    const int wid = tid >> 6;
    const int wo = wid >> 1, wt = wid & 1;
    const int o0 = blockIdx.x * 128;
    const int i0 = blockIdx.y * 32;
    const int t0 = blockIdx.z * 128;
    const int l15 = lane & 15, l4 = lane >> 4;

    #pragma unroll
    for (int it = 0; it < 4; ++it) {
        int e = it * 2048 + tid * 8;
        int r = e >> 5, col = e & 31;
        int p = t0 - 63 + r;
        bf16x8 v = {};
        if (p >= 0 && p < 2048)
            v = *reinterpret_cast<const bf16x8*>(Xg + (size_t)p * I_TOTAL + i0 + col);
        *reinterpret_cast<bf16x8*>(&Xt[r][col]) = v;
    }

    f32x4 acc[4][4];
    #pragma unroll
    for (int a = 0; a < 4; ++a)
        #pragma unroll
        for (int b = 0; b < 4; ++b) acc[a][b] = (f32x4){0.f, 0.f, 0.f, 0.f};

    const size_t wstride = (size_t)O_TOTAL * I_TOTAL;
    bf16x8 wreg[8];
    #pragma unroll
    for (int it = 0; it < 8; ++it) {
        int e = it * 2048 + tid * 8;
        int s = e >> 12; int kloc = s >> 1, hl = s & 1;
        const u16* src = hl ? Wlo : Wh;
        wreg[it] = *reinterpret_cast<const bf16x8*>(
            src + (size_t)kloc * wstride + (size_t)(o0 + ((e >> 5) & 127)) * I_TOTAL + i0 + (e & 31));
    }

    for (int tp = 0; tp < 64; ++tp) {
        __syncthreads();
        #pragma unroll
        for (int it = 0; it < 8; ++it) {
            int e = it * 2048 + tid * 8;
            *reinterpret_cast<bf16x8*>(&Ws[e >> 12][(e >> 5) & 127][e & 31]) = wreg[it];
        }
        if (tp + 1 < 64) {
            int k0n = (tp + 1) * 2;
            #pragma unroll
            for (int it = 0; it < 8; ++it) {
                int e = it * 2048 + tid * 8;
                int s = e >> 12; int kloc = s >> 1, hl = s & 1;
                const u16* src = hl ? Wlo : Wh;
                wreg[it] = *reinterpret_cast<const bf16x8*>(
                    src + (size_t)(k0n + kloc) * wstride + (size_t)(o0 + ((e >> 5) & 127)) * I_TOTAL + i0 + (e & 31));
            }
        }
        __syncthreads();
        #pragma unroll
        for (int kl = 0; kl < 2; ++kl) {
            const int k = tp * 2 + kl;
            bf16x8 B[4];
            #pragma unroll
            for (int b = 0; b < 4; ++b) {
                int row = wt * 64 + b * 16 + l15 + k;
                B[b] = *reinterpret_cast<const bf16x8*>(&Xt[row][l4 * 8]);
            }
            #pragma unroll
            for (int hl = 0; hl < 2; ++hl) {
                #pragma unroll
                for (int a = 0; a < 4; ++a) {
                    bf16x8 A = *reinterpret_cast<const bf16x8*>(
                        &Ws[kl * 2 + hl][wo * 64 + a * 16 + l15][l4 * 8]);
                    #pragma unroll
                    for (int b = 0; b < 4; ++b)
                        acc[a][b] = __builtin_amdgcn_mfma_f32_16x16x32_bf16(A, B[b], acc[a][b], 0, 0, 0);
                }
            }
        }
    }

    float* outp = Yp + (size_t)blockIdx.y * ((size_t)O_TOTAL * 2048);
    #pragma unroll
    for (int a = 0; a < 4; ++a)
        #pragma unroll
        for (int b = 0; b < 4; ++b) {
            int col = t0 + wt * 64 + b * 16 + l15;
            #pragma unroll
            for (int r = 0; r < 4; ++r) {
                int row = o0 + wo * 64 + a * 16 + l4 * 4 + r;
                outp[(size_t)row * 2048 + col] = acc[a][b][r];
            }
        }
}

// combine K-split partials + bias + silu -> fp32
template<int KSPLIT>
__global__ void conv_combine_silu(const float* __restrict__ Yp, const float* __restrict__ bias,
                                  float* __restrict__ out, int total)
{
    int f = blockIdx.x * 256 + threadIdx.x;
    if (f >= total) return;
    float s = bias[f >> 11];
    #pragma unroll
    for (int z = 0; z < KSPLIT; ++z) s += Yp[(size_t)z * total + f];
    out[f] = s / (1.f + __expf(-s));
}

// combine + bias + silu -> split bf16 (for conv1 -> in_proj GEMM)
template<int KSPLIT>
__global__ void conv_combine_silu_split(const float* __restrict__ Yp, const float* __restrict__ bias,
                                        u16* __restrict__ oh, u16* __restrict__ ol, int total)
{
    int f = blockIdx.x * 256 + threadIdx.x;
    if (f >= total) return;
    float s = bias[f >> 11];
    #pragma unroll
    for (int z = 0; z < KSPLIT; ++z) s += Yp[(size_t)z * total + f];
    float v = s / (1.f + __expf(-s));
    u16 hh = bf16rn(v);
    oh[f] = hh;
    ol[f] = bf16rn(v - bf16tof(hh));
}

// ---------------------------------------------------------------------------
// Split-bf16 MFMA GEMM: C[M][N] = A[M][K]*B[N][K]^T via Ah*Bh + Ah*Bl + Al*Bh.
// Tile 128Mx64N, BK=64, 256 thr = 4 waves (2Mx2N), wave 64Mx32N (4x2 frags).
// ---------------------------------------------------------------------------
__global__ __launch_bounds__(256)
void gemm_mfma_split(const u16* __restrict__ Ah, const u16* __restrict__ Al,
                     const u16* __restrict__ Bh, const u16* __restrict__ Bl,
                     float* __restrict__ C, int M, int N, int K)
{
    __shared__ u16 As[2][128][72];
    __shared__ u16 Bs[2][64][72];
    const int tid = threadIdx.x, lane = tid & 63, wid = tid >> 6;
    const int wm = wid >> 1, wn = wid & 1;
    const int m0 = blockIdx.x * 128, n0 = blockIdx.y * 64;
    const int l15 = lane & 15, l4 = lane >> 4;

    f32x4 acc[4][2];
    #pragma unroll
    for (int a = 0; a < 4; ++a)
        #pragma unroll
        for (int b = 0; b < 2; ++b) acc[a][b] = (f32x4){0.f, 0.f, 0.f, 0.f};

    for (int k0 = 0; k0 < K; k0 += 64) {
        __syncthreads();
        #pragma unroll
        for (int it = 0; it < 4; ++it) {
            int e = it * 2048 + tid * 8;
            int r = e >> 6, cc = e & 63;
            *reinterpret_cast<bf16x8*>(&As[0][r][cc]) =
                *reinterpret_cast<const bf16x8*>(Ah + (size_t)(m0 + r) * K + k0 + cc);
            *reinterpret_cast<bf16x8*>(&As[1][r][cc]) =
                *reinterpret_cast<const bf16x8*>(Al + (size_t)(m0 + r) * K + k0 + cc);
        }
        #pragma unroll
        for (int it = 0; it < 2; ++it) {
            int e = it * 2048 + tid * 8;
            int r = e >> 6, cc = e & 63;
            bf16x8 vh = {}, vl = {};
            if (n0 + r < N) {
                vh = *reinterpret_cast<const bf16x8*>(Bh + (size_t)(n0 + r) * K + k0 + cc);
                vl = *reinterpret_cast<const bf16x8*>(Bl + (size_t)(n0 + r) * K + k0 + cc);
            }
            *reinterpret_cast<bf16x8*>(&Bs[0][r][cc]) = vh;
            *reinterpret_cast<bf16x8*>(&Bs[1][r][cc]) = vl;
        }
        __syncthreads();
        #pragma unroll
        for (int ks = 0; ks < 2; ++ks) {
            bf16x8 afh[4], afl[4], bfh[2], bfl[2];
            #pragma unroll
            for (int b = 0; b < 2; ++b) {
                bfh[b] = *reinterpret_cast<const bf16x8*>(&Bs[0][wn*32 + b*16 + l15][ks*32 + l4*8]);
                bfl[b] = *reinterpret_cast<const bf16x8*>(&Bs[1][wn*32 + b*16 + l15][ks*32 + l4*8]);
            }
            #pragma unroll
            for (int a = 0; a < 4; ++a) {
                afh[a] = *reinterpret_cast<const bf16x8*>(&As[0][wm*64 + a*16 + l15][ks*32 + l4*8]);
                afl[a] = *reinterpret_cast<const bf16x8*>(&As[1][wm*64 + a*16 + l15][ks*32 + l4*8]);
            }
            #pragma unroll
            for (int a = 0; a < 4; ++a)
                #pragma unroll
                for (int b = 0; b < 2; ++b) {
                    acc[a][b] = __builtin_amdgcn_mfma_f32_16x16x32_bf16(afh[a], bfh[b], acc[a][b], 0, 0, 0);
                    acc[a][b] = __builtin_amdgcn_mfma_f32_16x16x32_bf16(afh[a], bfl[b], acc[a][b], 0, 0, 0);
                    acc[a][b] = __builtin_amdgcn_mfma_f32_16x16x32_bf16(afl[a], bfh[b], acc[a][b], 0, 0, 0);
                }
        }
    }
    #pragma unroll
    for (int a = 0; a < 4; ++a)
        #pragma unroll
        for (int b = 0; b < 2; ++b) {
            int col = n0 + wn * 32 + b * 16 + l15;
            if (col < N) {
                #pragma unroll
                for (int r = 0; r < 4; ++r) {
                    int row = m0 + wm * 64 + a * 16 + l4 * 4 + r;
                    C[(size_t)row * N + col] = acc[a][b][r];
                }
            }
        }
}

// ---------------------------------------------------------------------------
// depthwise conv (7 taps) + silu -> fp32 xc AND split bf16 (for x_proj GEMM)
// ---------------------------------------------------------------------------
__global__ void dwconv_silu_split(const float* __restrict__ xz, const float* __restrict__ w7,
                                  const float* __restrict__ cb, float* __restrict__ xc,
                                  u16* __restrict__ oh, u16* __restrict__ ol, int dir)
{
    int idx = blockIdx.x * 256 + threadIdx.x;
    if (idx >= HT * 256) return;
    int c = idx & 255;
    int ht = idx >> 8;
    int h = ht >> 11, t = ht & 2047;
    float s = cb[c];
    #pragma unroll
    for (int k = 0; k < 7; ++k) {
        int tt = dir ? (t + 6 - k) : (t - 6 + k);
        if (tt >= 0 && tt < SEQL)
            s += w7[c * 7 + k] * xz[((size_t)(h << 11) + tt) * 512 + c];
    }
    float v = s / (1.f + __expf(-s));
    xc[idx] = v;
    u16 hh = bf16rn(v);
    oh[idx] = hh;
    ol[idx] = bf16rn(v - bf16tof(hh));
}

__global__ void delta_softplus(const float* __restrict__ dbc, const float* __restrict__ dtw,
                               const float* __restrict__ dtb, float* __restrict__ delta)
{
    int idx = blockIdx.x * 256 + threadIdx.x;
    if (idx >= HT * 256) return;
    int c = idx & 255;
    int ht = idx >> 8;
    const float* dr = dbc + (size_t)ht * 264;
    float s = dtb[c];
    #pragma unroll
    for (int r = 0; r < 8; ++r) s += dr[r] * dtw[c * 8 + r];
    delta[idx] = (s > 20.f) ? s : log1pf(__expf(s));
}

// ---------------------------------------------------------------------------
// Chunked selective scan, lane=d layout, n split 4 ways (n0 = nh*32).
// A2[n*256+d] = -exp(A_log[d*128+n]) * log2(e); decays via hardware exp2.
// Q layout: [hd(8)][chunk(NC)][n(128)][d(256)]; S: [hd][chunk][d] = sum delta.
// grid (4, NC, 8), block 256 = 4 waves (wave w -> d = w*64+lane).
// pass3 y combined across the 4 n-quarters via fp32 atomicAdd on zeroed ys.
// ---------------------------------------------------------------------------
template<int NC>
__global__ __launch_bounds__(256)
void scan_pass1(const float* __restrict__ del_f, const float* __restrict__ dbc_f,
                const float* __restrict__ xc_f,
                const float* __restrict__ del_b, const float* __restrict__ dbc_b,
                const float* __restrict__ xc_b,
                const float* __restrict__ A2, float* __restrict__ Q, float* __restrict__ S)
{
    constexpr int CH = 2048 / NC;
    __shared__ float2 Bs2[64][16];
    const int tid = threadIdx.x, lane = tid & 63, wv = tid >> 6;
    const int nh = blockIdx.x, c = blockIdx.y, hd = blockIdx.z;
    const int dir = hd >> 2, h = hd & 3;
    const int n0 = nh * 32, d = wv * 64 + lane;
    const float* del = dir ? del_b : del_f;
    const float* dbc = dir ? dbc_b : dbc_f;
    const float* xc  = dir ? xc_b  : xc_f;

    float A[32], hreg[32];
    #pragma unroll
    for (int j = 0; j < 32; ++j) { A[j] = A2[(size_t)(n0 + j) * 256 + d]; hreg[j] = 0.f; }
    float sS = 0.f;

    for (int seg = 0; seg < CH / 64; ++seg) {
        __syncthreads();
        for (int e = tid; e < 64 * 16; e += 256) {
            int t = e >> 4, j2 = e & 15;
            int g = c * CH + seg * 64 + t;
            int tt = dir ? 2047 - g : g;
            Bs2[t][j2] = *reinterpret_cast<const float2*>(
                &dbc[((size_t)h * 2048 + tt) * 264 + 8 + n0 + 2 * j2]);
        }
        __syncthreads();

        int g0 = c * CH + seg * 64;
        int tt0 = dir ? 2047 - g0 : g0;
        size_t htc = (size_t)h * 2048 + tt0;
        float dlt = del[htc * 256 + d];
        float u   = xc[htc * 256 + d];
        #pragma unroll 1
        for (int t = 0; t < 64; ++t) {
            float dltn = 0.f, un = 0.f;
            size_t htn = htc;
            if (t < 63) {
                int g = g0 + t + 1;
                int tt = dir ? 2047 - g : g;
                htn = (size_t)h * 2048 + tt;
                dltn = del[htn * 256 + d];
                un   = xc[htn * 256 + d];
            }
            float du = dlt * u;
            sS += dlt;
            #pragma unroll
            for (int j2 = 0; j2 < 16; ++j2) {
                float2 bb = Bs2[t][j2];
                hreg[2*j2]   = EXP2(A[2*j2]   * dlt) * hreg[2*j2]   + du * bb.x;
                hreg[2*j2+1] = EXP2(A[2*j2+1] * dlt) * hreg[2*j2+1] + du * bb.y;
            }
            htc = htn; dlt = dltn; u = un;
        }
    }
    size_t qb = (((size_t)hd * NC + c) * 128) * 256;
    #pragma unroll
    for (int j = 0; j < 32; ++j) Q[qb + (size_t)(n0 + j) * 256 + d] = hreg[j];
    if (nh == 0) S[((size_t)hd * NC + c) * 256 + d] = sS;
}

template<int NC>
__global__ void scan_pass2(const float* __restrict__ A2, const float* __restrict__ S,
                           float* __restrict__ Q)
{
    int idx = blockIdx.x * 256 + threadIdx.x;   // 8*128*256 = 262144
    int hd = idx >> 15, rem = idx & 32767, n = rem >> 8, d = rem & 255;
    float A = A2[(size_t)n * 256 + d];
    float hcur = 0.f;
    for (int c = 0; c < NC; ++c) {
        size_t o = (((size_t)hd * NC + c) * 128 + n) * 256 + d;
        float q = Q[o];
        Q[o] = hcur;                                    // chunk-start state
        hcur = EXP2(A * S[((size_t)hd * NC + c) * 256 + d]) * hcur + q;
    }
}

template<int NC>
__global__ __launch_bounds__(256)
void scan_pass3(const float* __restrict__ del_f, const float* __restrict__ dbc_f,
                const float* __restrict__ xc_f, float* __restrict__ ys_f,
                const float* __restrict__ del_b, const float* __restrict__ dbc_b,
                const float* __restrict__ xc_b, float* __restrict__ ys_b,
                const float* __restrict__ A2, const float* __restrict__ Q)
{
    constexpr int CH = 2048 / NC;
    __shared__ float4 BC4[64][16];
    const int tid = threadIdx.x, lane = tid & 63, wv = tid >> 6;
    const int nh = blockIdx.x, c = blockIdx.y, hd = blockIdx.z;
    const int dir = hd >> 2, h = hd & 3;
    const int n0 = nh * 32, d = wv * 64 + lane;
    const float* del = dir ? del_b : del_f;
    const float* dbc = dir ? dbc_b : dbc_f;
    const float* xc  = dir ? xc_b  : xc_f;
    float* ys        = dir ? ys_b  : ys_f;

    float A[32], hreg[32];
    size_t qb = (((size_t)hd * NC + c) * 128) * 256;
    #pragma unroll
    for (int j = 0; j < 32; ++j) {
        A[j] = A2[(size_t)(n0 + j) * 256 + d];
        hreg[j] = Q[qb + (size_t)(n0 + j) * 256 + d];
    }

    for (int seg = 0; seg < CH / 64; ++seg) {
        __syncthreads();
        for (int e = tid; e < 64 * 16; e += 256) {
            int t = e >> 4, j2 = e & 15;
            int g = c * CH + seg * 64 + t;
            int tt = dir ? 2047 - g : g;
            size_t ht = (size_t)h * 2048 + tt;
            float2 b2 = *reinterpret_cast<const float2*>(&dbc[ht * 264 + 8   + n0 + 2 * j2]);
            float2 c2 = *reinterpret_cast<const float2*>(&dbc[ht * 264 + 136 + n0 + 2 * j2]);
            BC4[t][j2] = (float4){b2.x, c2.x, b2.y, c2.y};
        }
        __syncthreads();

        int g0 = c * CH + seg * 64;
        int tt0 = dir ? 2047 - g0 : g0;
        size_t htc = (size_t)h * 2048 + tt0;
        float dlt = del[htc * 256 + d];
        float u   = xc[htc * 256 + d];
        #pragma unroll 1
        for (int t = 0; t < 64; ++t) {
            float dltn = 0.f, un = 0.f;
            size_t htn = htc;
            if (t < 63) {
                int g = g0 + t + 1;
                int tt = dir ? 2047 - g : g;
                htn = (size_t)h * 2048 + tt;
                dltn = del[htn * 256 + d];
                un   = xc[htn * 256 + d];
            }
            float du = dlt * u;
            float y0 = 0.f, y1 = 0.f;
            #pragma unroll
            for (int j2 = 0; j2 < 16; ++j2) {
                float4 bc = BC4[t][j2];
                hreg[2*j2]   = EXP2(A[2*j2]   * dlt) * hreg[2*j2]   + du * bc.x;
                y0 += hreg[2*j2] * bc.y;
                hreg[2*j2+1] = EXP2(A[2*j2+1] * dlt) * hreg[2*j2+1] + du * bc.z;
                y1 += hreg[2*j2+1] * bc.w;
            }
            atomicAdd(&ys[htc * 256 + d], y0 + y1);
            htc = htn; dlt = dltn; u = un;
        }
    }
}

// A2[n*256+d] = -exp(A_log[d*128+n]) * log2(e)
__global__ void negexp_transpose(const float* __restrict__ A_log, float* __restrict__ A2)
{
    int idx = blockIdx.x * 256 + threadIdx.x;   // 32768
    int n = idx >> 8, d = idx & 255;
    A2[idx] = -__expf(A_log[d * 128 + n]) * LOG2E;
}

// y = (ys + xc*D) * silu(z) -> split bf16 (feeds out_proj GEMM only)
__global__ void ycombine_split(const float* __restrict__ ysin, const float* __restrict__ xc,
                               const float* __restrict__ xz, const float* __restrict__ Dp,
                               u16* __restrict__ oh, u16* __restrict__ ol)
{
    int idx = blockIdx.x * 256 + threadIdx.x;
    if (idx >= HT * 256) return;
    int c = idx & 255;
    size_t ht = idx >> 8;
    float z = xz[ht * 512 + 256 + c];
    float y = (ysin[idx] + xc[idx] * Dp[c]) * (z / (1.f + __expf(-z)));
    u16 hh = bf16rn(y);
    oh[idx] = hh;
    ol[idx] = bf16rn(y - bf16tof(hh));
}

__global__ __launch_bounds__(256)
void rmsnorm_add(const float* __restrict__ xf, const float* __restrict__ xb,
                 const float* __restrict__ w, float* __restrict__ xn)
{
    int row  = blockIdx.x * 4 + (threadIdx.x >> 6);
    int lane = threadIdx.x & 63;
    size_t base = (size_t)row * 128;
    float a0 = xf[base + lane]      + xb[base + lane];
    float a1 = xf[base + 64 + lane] + xb[base + 64 + lane];
    float ss = a0 * a0 + a1 * a1;
    #pragma unroll
    for (int off = 32; off; off >>= 1) ss += __shfl_xor(ss, off);
    float r = rsqrtf(ss / 128.f + 1e-8f);
    xn[base + lane]      = a0 * r * w[lane];
    xn[base + 64 + lane] = a1 * r * w[64 + lane];
}

// ---------------------------------------------------------------------------
extern "C" void kernel_launch(void* const* d_in, const int* in_sizes, int n_in,
                              void* d_out, int out_size, void* d_ws, size_t ws_size,
                              hipStream_t stream)
{
    const float* x        = (const float*)d_in[0];
    const float* icw      = (const float*)d_in[1];
    const float* icb      = (const float*)d_in[2];
    const float* ocw      = (const float*)d_in[3];
    const float* ocb      = (const float*)d_in[4];
    const float* in_proj  = (const float*)d_in[5];
    const float* mconv_w  = (const float*)d_in[6];
    const float* mconv_b  = (const float*)d_in[7];
    const float* x_proj   = (const float*)d_in[8];
    const float* dt_w     = (const float*)d_in[9];
    const float* dt_b     = (const float*)d_in[10];
    const float* A_log    = (const float*)d_in[11];
    const float* Dp       = (const float*)d_in[12];
    const float* out_proj = (const float*)d_in[13];
    const float* norm_w   = (const float*)d_in[14];
    float* out = (float*)d_out;
    (void)in_sizes; (void)n_in; (void)out_size;

    float* w = (float*)d_ws;
    size_t off = 0;
    auto alloc = [&](size_t n) { float* p = w + off; off += n; return p; };
    float* p12   = alloc((size_t)4 * 1048576);  // conv1 partials; xc splits; W2l
    float* xp    = alloc(1048576);              // conv1 out as split bf16 (xp_h/xp_l)
    float* xz    = alloc((size_t)HT * 512);     // alias: Wt1h (before step 2)
    float* xc_f  = alloc((size_t)HT * 256);     // alias: Wt1l (pre-3), xn2t (post-7)
    float* xc_b  = alloc((size_t)HT * 256);
    float* dbc_f = alloc((size_t)HT * 264);
    float* dbc_b = alloc((size_t)HT * 264);
    float* del_f = alloc((size_t)HT * 256);
    float* del_b = alloc((size_t)HT * 256);
    float* ys_f  = alloc((size_t)HT * 256);     // ys_f+ys_b reused as conv2 partials
    float* ys_b  = alloc((size_t)HT * 256);
    float* xfo   = alloc((size_t)HT * 128);     // alias: xb1t (before step 8)
    float* xbo   = alloc((size_t)HT * 128);
    float* xn    = alloc((size_t)HT * 128);
    float* A2    = alloc(32768);                // -exp(A_log)*log2e, [n][d]
    float* S     = alloc(65536);                // chunk delta sums [hd][NC][d]
    float* Wsp   = alloc(262144);               // split projection weights (u16 packed)
    size_t remaining = ws_size / 4 - off;
    const int NC = (remaining >= (size_t)8 * 32 * 128 * 256) ? 32 : 16;
    float* Q = alloc((size_t)8 * NC * 128 * 256);

    // bf16 aliases (disjoint lifetimes)
    u16* Wt1h = (u16*)xz;     // dead before step 2
    u16* Wt1l = (u16*)xc_f;   // spans xc_f+xc_b; dead before step 3
    u16* xb1t = (u16*)xfo;    // dead before step 8
    u16* W2h  = (u16*)Q;      // written at 9.5 (Q + ys-splits dead)
    u16* W2l  = (u16*)p12;    // written at 9.5 (xc splits dead)
    u16* xn2t = (u16*)xc_f;   // written after ycombine (xc dead)
    float* cp2 = ys_f;        // conv2 partials: 16 x 262144 = ys_f+ys_b

    // split projection weights (in Wsp, u16 offsets)
    u16* W16 = (u16*)Wsp;
    u16* ip_h  = W16;           u16* ip_l  = W16 + 65536;
    u16* xpj_h = W16 + 131072;  u16* xpj_l = W16 + 198656;
    u16* opj_h = W16 + 266240;  u16* opj_l = W16 + 299008;
    // split activations (aliased; disjoint from their producers' inputs)
    u16* xp_h  = (u16*)xp;                  u16* xp_l  = (u16*)xp + 1048576;
    u16* xcf_h = (u16*)p12;                 u16* xcf_l = (u16*)(p12 + 1048576);
    u16* xcb_h = (u16*)(p12 + 2097152);     u16* xcb_l = (u16*)(p12 + 3145728);
    u16* ysf_h = (u16*)Q;                   u16* ysf_l = (u16*)(Q + 1048576);
    u16* ysb_h = (u16*)(Q + 2097152);       u16* ysb_l = (u16*)(Q + 3145728);

    // 0) transposed bf16 weights/inputs for conv1; scan A2; proj weight splits
    transpose_cast<true><<<dim3(4, 2048), 256, 0, stream>>>(icw, Wt1h, Wt1l, 512 * 128, 128);
    transpose_cast<false><<<dim3(64, 4), 256, 0, stream>>>(x, xb1t, nullptr, 128, 2048);
    negexp_transpose<<<128, 256, 0, stream>>>(A_log, A2);
    cast_split<<<64, 256, 0, stream>>>(in_proj, ip_h, ip_l, 65536);
    cast_split<<<66, 256, 0, stream>>>(x_proj, xpj_h, xpj_l, 67584);
    cast_split<<<32, 256, 0, stream>>>(out_proj, opj_h, opj_l, 32768);

    // 1) input conv via MFMA (KSPLIT=4) + bias + silu -> split bf16
    conv_mfma<512, 128><<<dim3(4, 4, 16), 256, 0, stream>>>(xb1t, Wt1h, Wt1l, p12);
    conv_combine_silu_split<4><<<4096, 256, 0, stream>>>(p12, icb, xp_h, xp_l, 512 * 2048);

    // 2) in_proj GEMM: xz = xp @ in_proj^T  (8192x512, K=128), split MFMA
    gemm_mfma_split<<<dim3(64, 8), 256, 0, stream>>>(xp_h, xp_l, ip_h, ip_l, xz, HT, 512, 128);

    // 3) depthwise conv + silu (fp32 + split), both directions
    dwconv_silu_split<<<8192, 256, 0, stream>>>(xz, mconv_w, mconv_b, xc_f, xcf_h, xcf_l, 0);
    dwconv_silu_split<<<8192, 256, 0, stream>>>(xz, mconv_w, mconv_b, xc_b, xcb_h, xcb_l, 1);

    // 4) x_proj GEMMs: dbc = xc @ x_proj^T  (8192x264, K=256), split MFMA
    gemm_mfma_split<<<dim3(64, 5), 256, 0, stream>>>(xcf_h, xcf_l, xpj_h, xpj_l, dbc_f, HT, 264, 256);
    gemm_mfma_split<<<dim3(64, 5), 256, 0, stream>>>(xcb_h, xcb_l, xpj_h, xpj_l, dbc_b, HT, 264, 256);

    // 5) delta = softplus(dt @ dt_w^T + dt_b)
    delta_softplus<<<8192, 256, 0, stream>>>(dbc_f, dt_w, dt_b, del_f);
    delta_softplus<<<8192, 256, 0, stream>>>(dbc_b, dt_w, dt_b, del_b);

    // 6) chunked selective scan (lane=d, 4-way n split), fwd+bwd
    hipMemsetAsync(ys_f, 0, (size_t)HT * 256 * 4, stream);
    hipMemsetAsync(ys_b, 0, (size_t)HT * 256 * 4, stream);
    if (NC == 32) {
        scan_pass1<32><<<dim3(4, 32, 8), 256, 0, stream>>>(del_f, dbc_f, xc_f,
                                                           del_b, dbc_b, xc_b, A2, Q, S);
        scan_pass2<32><<<1024, 256, 0, stream>>>(A2, S, Q);
        scan_pass3<32><<<dim3(4, 32, 8), 256, 0, stream>>>(del_f, dbc_f, xc_f, ys_f,
                                                           del_b, dbc_b, xc_b, ys_b, A2, Q);
    } else {
        scan_pass1<16><<<dim3(4, 16, 8), 256, 0, stream>>>(del_f, dbc_f, xc_f,
                                                           del_b, dbc_b, xc_b, A2, Q, S);
        scan_pass2<16><<<1024, 256, 0, stream>>>(A2, S, Q);
        scan_pass3<16><<<dim3(4, 16, 8), 256, 0, stream>>>(del_f, dbc_f, xc_f, ys_f,
                                                           del_b, dbc_b, xc_b, ys_b, A2, Q);
    }

    // 7) y = (ys + xc*D) * silu(z) -> split bf16 (in Q region; Q states dead)
    ycombine_split<<<8192, 256, 0, stream>>>(ys_f, xc_f, xz, Dp, ysf_h, ysf_l);
    ycombine_split<<<8192, 256, 0, stream>>>(ys_b, xc_b, xz, Dp, ysb_h, ysb_l);

    // 8) out_proj GEMMs (8192x128, K=256), split MFMA
    gemm_mfma_split<<<dim3(64, 2), 256, 0, stream>>>(ysf_h, ysf_l, opj_h, opj_l, xfo, HT, 128, 256);
    gemm_mfma_split<<<dim3(64, 2), 256, 0, stream>>>(ysb_h, ysb_l, opj_h, opj_l, xbo, HT, 128, 256);

    // 9) rmsnorm(xf + xb)
    rmsnorm_add<<<2048, 256, 0, stream>>>(xfo, xbo, norm_w, xn);

    // 9.5) transposed bf16 for conv2 (xn is [512][2048] flat-channel view)
    transpose_cast<false><<<dim3(64, 16), 256, 0, stream>>>(xn, xn2t, nullptr, 512, 2048);
    transpose_cast<true><<<dim3(4, 2048), 256, 0, stream>>>(ocw, W2h, W2l, 128 * 512, 128);

    // 10) output conv via MFMA (KSPLIT=16) + bias + silu -> d_out
    conv_mfma<128, 512><<<dim3(1, 16, 16), 256, 0, stream>>>(xn2t, W2h, W2l, cp2);
    conv_combine_silu<16><<<1024, 256, 0, stream>>>(cp2, ocb, out, 128 * 2048);
}